// Round 4
// baseline (360.927 us; speedup 1.0000x reference)
//
#include <hip/hip_runtime.h>

#define Bsz 64
#define Lsz 4096
#define Dsz 512
#define Hsz 512
#define Usz 256
#define LT  64
#define NLB (Lsz / LT)          // 64 L-tiles per batch
#define TPB 16                  // tiles per block
#define NQB (NLB / TPB)         // 4 blocks per batch -> 256 blocks total

typedef __attribute__((ext_vector_type(8))) short s8v;     // bf16x8 MFMA frag
typedef __attribute__((ext_vector_type(4))) float f4v;
typedef __attribute__((ext_vector_type(4))) unsigned short u16x4;

// XOR swizzle, c in shorts, 8-short (16B) granule rotated by row&7
#define SWZ(row, c) ((c) ^ (((row) & 7) << 3))

__device__ __forceinline__ unsigned short f2bf(float f) {
    unsigned int u = __float_as_uint(f);
    u += 0x7FFFu + ((u >> 16) & 1u);   // RNE
    return (unsigned short)(u >> 16);
}
__device__ __forceinline__ float bf2f(unsigned int lo16) {
    return __uint_as_float(lo16 << 16);
}
// barrier that drains LDS only (NOT vmcnt) -> feature loads stay in flight
__device__ __forceinline__ void barrier_lds() {
    asm volatile("s_waitcnt lgkmcnt(0)" ::: "memory");
    __builtin_amdgcn_s_barrier();
}

// ws layout
//   [0,     256K) : W1T bf16 [256][512]
//   [256K,  512K) : hp_part f32 [4][64][256]
//   [512K, 1536K) : el_arr f32 [64][4096]
//   [1536K,1552K) : eden f32 [64][64]
//   [1552K,2064K) : pctx f32 [64][4][512]

__global__ __launch_bounds__(256) void k_prep(const float* __restrict__ W1,
                                              const float* __restrict__ hidden,
                                              const float* __restrict__ W2,
                                              unsigned short* __restrict__ W1T,
                                              float* __restrict__ hp_part) {
    int blk = blockIdx.x, tid = threadIdx.x;
    if (blk < 512) {
        int e = blk * 256 + tid;          // coalesced over W1 [512][256]
        int k = e >> 8, u = e & 255;
        W1T[u * Dsz + k] = f2bf(W1[e]);
    } else {
        int idx = blk - 512;
        int kq = idx >> 6, b = idx & 63;  // K-quarter, batch
        const float* hrow = hidden + (size_t)b * Hsz + kq * 128;
        const float* w2p  = W2 + (size_t)(kq * 128) * Usz + tid;
        float a0 = 0.f, a1 = 0.f, a2 = 0.f, a3 = 0.f;
#pragma unroll 8
        for (int k = 0; k < 128; k += 4) {
            a0 = fmaf(hrow[k + 0], w2p[(size_t)(k + 0) * Usz], a0);
            a1 = fmaf(hrow[k + 1], w2p[(size_t)(k + 1) * Usz], a1);
            a2 = fmaf(hrow[k + 2], w2p[(size_t)(k + 2) * Usz], a2);
            a3 = fmaf(hrow[k + 3], w2p[(size_t)(k + 3) * Usz], a3);
        }
        hp_part[((size_t)kq * Bsz + b) * Usz + tid] = (a0 + a1) + (a2 + a3);
    }
}

// Persistent-tile fused kernel. 256 blocks x 1024 thr (16 waves).
// Block (b, qb) processes tiles lb = qb*16 .. qb*16+15 (64 L-rows each).
// Wave w owns U-cols [w*16, w*16+16).
__global__ __launch_bounds__(1024, 4) void k_score_ctx(
    const float* __restrict__ feat, const unsigned short* __restrict__ W1T,
    const float* __restrict__ hp_part, const float* __restrict__ W1b,
    const float* __restrict__ W2b, const float* __restrict__ Vk,
    const float* __restrict__ Vb, float* __restrict__ el_arr,
    float* __restrict__ eden, float* __restrict__ pctx)
{
    __shared__ __align__(16) unsigned short Abuf[2][LT][Dsz];  // 128 KiB dbuf
    __shared__ float hp[Usz], vv[Usz];
    __shared__ float spart[16][LT];
    __shared__ float el[LT];
    __shared__ float pc[4][Dsz];

    const int tid  = threadIdx.x;
    const int w    = tid >> 6;
    const int lane = tid & 63;
    const int lr   = lane & 15;
    const int lg   = lane >> 4;
    const int b    = blockIdx.x >> 2;
    const int qb   = blockIdx.x & 3;

    if (tid < Usz) {
        const float* hpb = hp_part + (size_t)b * Usz + tid;
        hp[tid] = (hpb[0] + hpb[Bsz * Usz]) + (hpb[2 * Bsz * Usz] + hpb[3 * Bsz * Usz])
                + W1b[tid] + W2b[tid];
        vv[tid] = Vk[tid];
    }

    const float* fbase = feat + ((size_t)b * Lsz + qb * TPB * LT) * Dsz;
    const int srow = tid >> 7;              // base row 0..7 (+8 per i)
    const int sc4  = (tid & 127) * 4;       // float col

    // ---- prologue: stage tile 0 ----
    f4v st[8];
#pragma unroll
    for (int i = 0; i < 8; ++i)
        st[i] = *reinterpret_cast<const f4v*>(fbase + (size_t)(i * 8 + srow) * Dsz + sc4);
#pragma unroll
    for (int i = 0; i < 8; ++i) {
        int row = i * 8 + srow;
        u16x4 o = { f2bf(st[i].x), f2bf(st[i].y), f2bf(st[i].z), f2bf(st[i].w) };
        *reinterpret_cast<u16x4*>(&Abuf[0][row][SWZ(row, sc4)]) = o;
    }
    barrier_lds();

    float c0 = 0.f, c1 = 0.f;               // running context (this thread's 2 dims)
    const int qr = tid >> 8;                // ctx row-quarter 0..3
    const int d0 = (tid & 255) * 2;

    const unsigned short* bp = W1T + (size_t)(w * 16 + lr) * Dsz + lg * 8;

    int cur = 0;
#pragma unroll 1
    for (int t = 0; t < TPB; ++t) {
        // (a') issue ALL B-frags first (L2-hot; retire before st in vmcnt FIFO)
        s8v ball[16];
#pragma unroll
        for (int ks = 0; ks < 16; ++ks)
            ball[ks] = *reinterpret_cast<const s8v*>(bp + ks * 32);

        // (a) issue next-tile feature loads (stay in flight across barriers)
        if (t < TPB - 1) {
            const float* fn = fbase + (size_t)(t + 1) * LT * Dsz;
#pragma unroll
            for (int i = 0; i < 8; ++i)
                st[i] = *reinterpret_cast<const f4v*>(fn + (size_t)(i * 8 + srow) * Dsz + sc4);
        }
        __builtin_amdgcn_sched_barrier(0);

        // (b) GEMM: 64 rows x 16 cols x K=512 from LDS
        const unsigned short (*A)[Dsz] = Abuf[cur];
        f4v acc[4];
#pragma unroll
        for (int mf = 0; mf < 4; ++mf) acc[mf] = (f4v){0.f, 0.f, 0.f, 0.f};
#pragma unroll
        for (int ks = 0; ks < 16; ++ks) {
            const int kof = ks * 32 + lg * 8;
#pragma unroll
            for (int mf = 0; mf < 4; ++mf) {
                const int row = mf * 16 + lr;
                s8v a = *reinterpret_cast<const s8v*>(&A[row][SWZ(row, kof)]);
                acc[mf] = __builtin_amdgcn_mfma_f32_16x16x32_bf16(a, ball[ks], acc[mf], 0, 0, 0);
            }
        }

        // (c) epilogue: sum over this wave's 16 cols of tanh(x)*V
        {
            const int col = w * 16 + lr;
            const float hpv = hp[col], vvv = vv[col];
            float rs[4][4];
#pragma unroll
            for (int mf = 0; mf < 4; ++mf)
#pragma unroll
                for (int r = 0; r < 4; ++r) {
                    float x = acc[mf][r] + hpv;
                    float e = __expf(2.f * x);
                    rs[mf][r] = (1.f - 2.f / (e + 1.f)) * vvv;   // tanh*V
                }
#pragma unroll
            for (int off = 1; off < 16; off <<= 1)
#pragma unroll
                for (int mf = 0; mf < 4; ++mf)
#pragma unroll
                    for (int r = 0; r < 4; ++r)
                        rs[mf][r] += __shfl_xor(rs[mf][r], off, 64);
            if (lr == 0)
#pragma unroll
                for (int mf = 0; mf < 4; ++mf)
#pragma unroll
                    for (int r = 0; r < 4; ++r)
                        spart[w][mf * 16 + lg * 4 + r] = rs[mf][r];
        }
        barrier_lds();

        // (d) scores -> exp -> per-tile denominator
        if (tid < LT) {
            float s = Vb[0];
#pragma unroll
            for (int ww = 0; ww < 16; ++ww) s += spart[ww][tid];
            float e = __expf(s);
            el[tid] = e;
            el_arr[(size_t)b * Lsz + (qb * TPB + t) * LT + tid] = e;
            float es = e;
#pragma unroll
            for (int off = 1; off < 64; off <<= 1) es += __shfl_xor(es, off, 64);
            if (tid == 0) eden[b * NLB + qb * TPB + t] = es;
        }
        barrier_lds();

        // (e) context accumulate from current LDS tile (16 rows per thread)
#pragma unroll
        for (int li = 0; li < 16; ++li) {
            int l = qr * 16 + li;
            unsigned int pk = *reinterpret_cast<const unsigned int*>(&Abuf[cur][l][SWZ(l, d0)]);
            float e = el[l];
            c0 = fmaf(e, bf2f(pk & 0xFFFFu), c0);
            c1 = fmaf(e, bf2f(pk >> 16), c1);
        }

        // (f) write staged regs -> other buffer (vmcnt wait happens here)
        if (t < TPB - 1) {
#pragma unroll
            for (int i = 0; i < 8; ++i) {
                int row = i * 8 + srow;
                u16x4 o = { f2bf(st[i].x), f2bf(st[i].y), f2bf(st[i].z), f2bf(st[i].w) };
                *reinterpret_cast<u16x4*>(&Abuf[cur ^ 1][row][SWZ(row, sc4)]) = o;
            }
        }
        barrier_lds();
        cur ^= 1;
    }

    // ---- final partial-context write ----
    pc[qr][d0]     = c0;
    pc[qr][d0 + 1] = c1;
    barrier_lds();
    if (tid < Dsz)
        pctx[((size_t)b * NQB + qb) * Dsz + tid] =
            (pc[0][tid] + pc[1][tid]) + (pc[2][tid] + pc[3][tid]);
}

__global__ __launch_bounds__(256) void k_finalize(const float* __restrict__ el_arr,
                                                  const float* __restrict__ eden,
                                                  const float* __restrict__ pctx,
                                                  float* __restrict__ ctx,
                                                  float* __restrict__ wout) {
    int blk = blockIdx.x, tid = threadIdx.x;
    int b = blk >> 2, qb = blk & 3;
    float s = eden[b * NLB + (tid & 63)];
#pragma unroll
    for (int off = 1; off < 64; off <<= 1) s += __shfl_xor(s, off, 64);
    float inv = 1.f / s;

    if (tid < 128) {
        int d = qb * 128 + tid;
        float c = 0.f;
#pragma unroll
        for (int p = 0; p < NQB; ++p) c += pctx[((size_t)b * NQB + p) * Dsz + d];
        ctx[(size_t)b * Dsz + d] = c * inv;
    }
#pragma unroll
    for (int i = 0; i < 4; ++i) {
        size_t idx = (size_t)b * Lsz + qb * 1024 + i * 256 + tid;
        wout[idx] = el_arr[idx] * inv;
    }
}

extern "C" void kernel_launch(void* const* d_in, const int* in_sizes, int n_in,
                              void* d_out, int out_size, void* d_ws, size_t ws_size,
                              hipStream_t stream) {
    const float* feat   = (const float*)d_in[0];
    const float* hidden = (const float*)d_in[1];
    const float* W1     = (const float*)d_in[2];
    const float* W1b    = (const float*)d_in[3];
    const float* W2     = (const float*)d_in[4];
    const float* W2b    = (const float*)d_in[5];
    const float* Vk     = (const float*)d_in[6];
    const float* Vb     = (const float*)d_in[7];

    unsigned short* w1t = (unsigned short*)d_ws;
    float* hp_part = (float*)((char*)d_ws + 256 * 1024);
    float* el_arr  = (float*)((char*)d_ws + 512 * 1024);
    float* eden    = (float*)((char*)d_ws + 1536 * 1024);
    float* pctx    = (float*)((char*)d_ws + 1552 * 1024);

    float* ctx  = (float*)d_out;              // [64, 512]
    float* wout = ctx + Bsz * Dsz;            // [64, 4096, 1]

    k_prep<<<768, 256, 0, stream>>>(W1, hidden, W2, w1t, hp_part);
    k_score_ctx<<<Bsz * NQB, 1024, 0, stream>>>(feat, w1t, hp_part, W1b, W2b,
                                                Vk, Vb, el_arr, eden, pctx);
    k_finalize<<<Bsz * NQB, 256, 0, stream>>>(el_arr, eden, pctx, ctx, wout);
}

// Round 5
// 326.564 us; speedup vs baseline: 1.1052x; 1.1052x over previous
//
#include <hip/hip_runtime.h>

#define Bsz 64
#define Lsz 4096
#define Dsz 512
#define Hsz 512
#define Usz 256
#define LT  32
#define NLB (Lsz / LT)          // 128 L-tiles per batch
#define TPB 16                  // tiles per block
#define NQB (NLB / TPB)         // 8 blocks per batch -> 512 blocks total
#define AW  520                 // LDS row stride (shorts): 1040B, 16B-aligned, 4-bank row shift

typedef __attribute__((ext_vector_type(8))) short s8v;     // bf16x8 MFMA frag
typedef __attribute__((ext_vector_type(4))) float f4v;
typedef __attribute__((ext_vector_type(4))) unsigned short u16x4;

__device__ __forceinline__ unsigned short f2bf(float f) {
    unsigned int u = __float_as_uint(f);
    u += 0x7FFFu + ((u >> 16) & 1u);   // RNE
    return (unsigned short)(u >> 16);
}
__device__ __forceinline__ float bf2f(unsigned int lo16) {
    return __uint_as_float(lo16 << 16);
}
// barrier draining LDS only (NOT vmcnt) -> global loads stay in flight
__device__ __forceinline__ void barrier_lds() {
    asm volatile("s_waitcnt lgkmcnt(0)" ::: "memory");
    __builtin_amdgcn_s_barrier();
}

// ws layout
//   [0,     256K) : W1T bf16 [256][512]
//   [256K,  512K) : hp_part f32 [4][64][256]
//   [512K, 1536K) : el_arr f32 [64][4096]
//   [1536K,1568K) : eden f32 [64][128]
//   [1568K,2592K) : pctx f32 [64][8][512]

__global__ __launch_bounds__(256) void k_prep(const float* __restrict__ W1,
                                              const float* __restrict__ hidden,
                                              const float* __restrict__ W2,
                                              unsigned short* __restrict__ W1T,
                                              float* __restrict__ hp_part) {
    int blk = blockIdx.x, tid = threadIdx.x;
    if (blk < 512) {
        int e = blk * 256 + tid;          // coalesced over W1 [512][256]
        int k = e >> 8, u = e & 255;
        W1T[u * Dsz + k] = f2bf(W1[e]);
    } else {
        int idx = blk - 512;
        int kq = idx >> 6, b = idx & 63;  // K-quarter, batch
        const float* hrow = hidden + (size_t)b * Hsz + kq * 128;
        const float* w2p  = W2 + (size_t)(kq * 128) * Usz + tid;
        float a0 = 0.f, a1 = 0.f, a2 = 0.f, a3 = 0.f;
#pragma unroll 8
        for (int k = 0; k < 128; k += 4) {
            a0 = fmaf(hrow[k + 0], w2p[(size_t)(k + 0) * Usz], a0);
            a1 = fmaf(hrow[k + 1], w2p[(size_t)(k + 1) * Usz], a1);
            a2 = fmaf(hrow[k + 2], w2p[(size_t)(k + 2) * Usz], a2);
            a3 = fmaf(hrow[k + 3], w2p[(size_t)(k + 3) * Usz], a3);
        }
        hp_part[((size_t)kq * Bsz + b) * Usz + tid] = (a0 + a1) + (a2 + a3);
    }
}

// 512 blocks x 512 thr (8 waves, 2 blocks/CU). Block (b,q8): 16 tiles of 32 rows.
// Wave w owns U-cols [w*32, w*32+32).
__global__ __launch_bounds__(512, 4) void k_score_ctx(
    const float* __restrict__ feat, const unsigned short* __restrict__ W1T,
    const float* __restrict__ hp_part, const float* __restrict__ W1b,
    const float* __restrict__ W2b, const float* __restrict__ Vk,
    const float* __restrict__ Vb, float* __restrict__ el_arr,
    float* __restrict__ eden, float* __restrict__ pctx)
{
    __shared__ __align__(16) unsigned short A[LT][AW];   // 33.3 KiB
    __shared__ float hp[Usz], vv[Usz];
    __shared__ float spart[8][LT];
    __shared__ float el[LT];
    __shared__ float pc[2][Dsz];

    const int tid  = threadIdx.x;
    const int w    = tid >> 6;
    const int lane = tid & 63;
    const int lr   = lane & 15;
    const int lg   = lane >> 4;
    const int b    = blockIdx.x >> 3;
    const int q8   = blockIdx.x & 7;

    if (tid < Usz) {
        const float* hpb = hp_part + (size_t)b * Usz + tid;
        hp[tid] = (hpb[0] + hpb[Bsz * Usz]) + (hpb[2 * Bsz * Usz] + hpb[3 * Bsz * Usz])
                + W1b[tid] + W2b[tid];
        vv[tid] = Vk[tid];
    }

    const float* fbase = feat + ((size_t)b * Lsz + q8 * (TPB * LT)) * Dsz;
    const int srow = tid >> 7;              // 0..3
    const int sc4  = (tid & 127) * 4;       // float col

    // ---- prologue: stage tile 0 ----
    f4v st[8];
#pragma unroll
    for (int i = 0; i < 8; ++i)
        st[i] = *reinterpret_cast<const f4v*>(fbase + (size_t)(i * 4 + srow) * Dsz + sc4);
#pragma unroll
    for (int i = 0; i < 8; ++i) {
        int row = i * 4 + srow;
        u16x4 o = { f2bf(st[i].x), f2bf(st[i].y), f2bf(st[i].z), f2bf(st[i].w) };
        *reinterpret_cast<u16x4*>(&A[row][sc4]) = o;
    }
    barrier_lds();

    float c0 = 0.f, c1 = 0.f;
    const int qr = tid >> 8;                // 0..1 (row half)
    const int d0 = (tid & 255) * 2;
    const unsigned short* bp = W1T + (size_t)(w * 32 + lr) * Dsz + lg * 8;

#pragma unroll 1
    for (int t = 0; t < TPB; ++t) {
        // (1) B-frags for K-half 1 (issued BEFORE st -> their waits never drain st)
        s8v bh[2][8];
#pragma unroll
        for (int k = 0; k < 8; ++k) {
            bh[0][k] = *reinterpret_cast<const s8v*>(bp + k * 32);
            bh[1][k] = *reinterpret_cast<const s8v*>(bp + 16 * Dsz + k * 32);
        }
        // (2) next-tile feature loads: in flight across the whole tile
        if (t < TPB - 1) {
            const float* fn = fbase + (size_t)(t + 1) * LT * Dsz;
#pragma unroll
            for (int i = 0; i < 8; ++i)
                st[i] = *reinterpret_cast<const f4v*>(fn + (size_t)(i * 4 + srow) * Dsz + sc4);
        }
        __builtin_amdgcn_sched_barrier(0);

        // (3) GEMM K-half 1
        f4v acc[2][2];
        acc[0][0] = (f4v){0.f, 0.f, 0.f, 0.f};
        acc[0][1] = (f4v){0.f, 0.f, 0.f, 0.f};
        acc[1][0] = (f4v){0.f, 0.f, 0.f, 0.f};
        acc[1][1] = (f4v){0.f, 0.f, 0.f, 0.f};
#pragma unroll
        for (int k = 0; k < 8; ++k) {
            const int kof = k * 32 + lg * 8;
#pragma unroll
            for (int mf = 0; mf < 2; ++mf) {
                const int row = mf * 16 + lr;
                s8v a = *reinterpret_cast<const s8v*>(&A[row][kof]);
                acc[mf][0] = __builtin_amdgcn_mfma_f32_16x16x32_bf16(a, bh[0][k], acc[mf][0], 0, 0, 0);
                acc[mf][1] = __builtin_amdgcn_mfma_f32_16x16x32_bf16(a, bh[1][k], acc[mf][1], 0, 0, 0);
            }
        }
        // (4) B-frags K-half 2 + GEMM K-half 2
#pragma unroll
        for (int k = 0; k < 8; ++k) {
            bh[0][k] = *reinterpret_cast<const s8v*>(bp + (8 + k) * 32);
            bh[1][k] = *reinterpret_cast<const s8v*>(bp + 16 * Dsz + (8 + k) * 32);
        }
#pragma unroll
        for (int k = 0; k < 8; ++k) {
            const int kof = (8 + k) * 32 + lg * 8;
#pragma unroll
            for (int mf = 0; mf < 2; ++mf) {
                const int row = mf * 16 + lr;
                s8v a = *reinterpret_cast<const s8v*>(&A[row][kof]);
                acc[mf][0] = __builtin_amdgcn_mfma_f32_16x16x32_bf16(a, bh[0][k], acc[mf][0], 0, 0, 0);
                acc[mf][1] = __builtin_amdgcn_mfma_f32_16x16x32_bf16(a, bh[1][k], acc[mf][1], 0, 0, 0);
            }
        }

        // (5) epilogue: per-row sum of tanh(x)*V over this wave's 32 cols
        {
            float rs[2][4];
#pragma unroll
            for (int mf = 0; mf < 2; ++mf)
#pragma unroll
                for (int r = 0; r < 4; ++r) rs[mf][r] = 0.f;
#pragma unroll
            for (int mf = 0; mf < 2; ++mf)
#pragma unroll
                for (int nf = 0; nf < 2; ++nf) {
                    int col = w * 32 + nf * 16 + lr;
                    float hpv = hp[col], vvv = vv[col];
#pragma unroll
                    for (int r = 0; r < 4; ++r) {
                        float x = acc[mf][nf][r] + hpv;
                        float e = __expf(2.f * x);
                        rs[mf][r] = fmaf(1.f - 2.f / (e + 1.f), vvv, rs[mf][r]);
                    }
                }
#pragma unroll
            for (int off = 1; off < 16; off <<= 1)
#pragma unroll
                for (int mf = 0; mf < 2; ++mf)
#pragma unroll
                    for (int r = 0; r < 4; ++r)
                        rs[mf][r] += __shfl_xor(rs[mf][r], off, 64);
            if (lr == 0)
#pragma unroll
                for (int mf = 0; mf < 2; ++mf)
#pragma unroll
                    for (int r = 0; r < 4; ++r)
                        spart[w][mf * 16 + lg * 4 + r] = rs[mf][r];
        }
        barrier_lds();

        // (6) scores -> exp -> per-tile denominator (wave 0, 32 lanes)
        if (tid < LT) {
            float s = Vb[0];
#pragma unroll
            for (int ww = 0; ww < 8; ++ww) s += spart[ww][tid];
            float e = __expf(s);
            el[tid] = e;
            el_arr[(size_t)b * Lsz + (q8 * TPB + t) * LT + tid] = e;
            float es = e;
#pragma unroll
            for (int off = 1; off < 32; off <<= 1) es += __shfl_xor(es, off, 64);
            if (tid == 0) eden[b * NLB + q8 * TPB + t] = es;
        }
        barrier_lds();

        // (7) context accumulate from current LDS tile
#pragma unroll
        for (int li = 0; li < 16; ++li) {
            int l = qr * 16 + li;
            unsigned int pk = *reinterpret_cast<const unsigned int*>(&A[l][d0]);
            float e = el[l];
            c0 = fmaf(e, bf2f(pk & 0xFFFFu), c0);
            c1 = fmaf(e, bf2f(pk >> 16), c1);
        }
        barrier_lds();

        // (8) write staged regs -> LDS (vmcnt wait lands here, fully covered)
        if (t < TPB - 1) {
#pragma unroll
            for (int i = 0; i < 8; ++i) {
                int row = i * 4 + srow;
                u16x4 o = { f2bf(st[i].x), f2bf(st[i].y), f2bf(st[i].z), f2bf(st[i].w) };
                *reinterpret_cast<u16x4*>(&A[row][sc4]) = o;
            }
        }
        barrier_lds();
    }

    // ---- final partial-context write ----
    pc[qr][d0]     = c0;
    pc[qr][d0 + 1] = c1;
    barrier_lds();
    pctx[((size_t)b * NQB + q8) * Dsz + tid] = pc[0][tid] + pc[1][tid];
}

__global__ __launch_bounds__(256) void k_finalize(const float* __restrict__ el_arr,
                                                  const float* __restrict__ eden,
                                                  const float* __restrict__ pctx,
                                                  float* __restrict__ ctx,
                                                  float* __restrict__ wout) {
    int blk = blockIdx.x, tid = threadIdx.x;
    int b = blk >> 2, dq = blk & 3;
    float s = eden[b * NLB + (tid & 63)] + eden[b * NLB + 64 + (tid & 63)];
#pragma unroll
    for (int off = 1; off < 64; off <<= 1) s += __shfl_xor(s, off, 64);
    float inv = 1.f / s;

    if (tid < 128) {
        int d = dq * 128 + tid;
        float c = 0.f;
#pragma unroll
        for (int p = 0; p < NQB; ++p) c += pctx[((size_t)b * NQB + p) * Dsz + d];
        ctx[(size_t)b * Dsz + d] = c * inv;
    }
#pragma unroll
    for (int i = 0; i < 4; ++i) {
        size_t idx = (size_t)b * Lsz + dq * 1024 + i * 256 + tid;
        wout[idx] = el_arr[idx] * inv;
    }
}

extern "C" void kernel_launch(void* const* d_in, const int* in_sizes, int n_in,
                              void* d_out, int out_size, void* d_ws, size_t ws_size,
                              hipStream_t stream) {
    const float* feat   = (const float*)d_in[0];
    const float* hidden = (const float*)d_in[1];
    const float* W1     = (const float*)d_in[2];
    const float* W1b    = (const float*)d_in[3];
    const float* W2     = (const float*)d_in[4];
    const float* W2b    = (const float*)d_in[5];
    const float* Vk     = (const float*)d_in[6];
    const float* Vb     = (const float*)d_in[7];

    unsigned short* w1t = (unsigned short*)d_ws;
    float* hp_part = (float*)((char*)d_ws + 256 * 1024);
    float* el_arr  = (float*)((char*)d_ws + 512 * 1024);
    float* eden    = (float*)((char*)d_ws + 1536 * 1024);
    float* pctx    = (float*)((char*)d_ws + 1568 * 1024);

    float* ctx  = (float*)d_out;              // [64, 512]
    float* wout = ctx + Bsz * Dsz;            // [64, 4096, 1]

    k_prep<<<768, 256, 0, stream>>>(W1, hidden, W2, w1t, hp_part);
    k_score_ctx<<<Bsz * NQB, 512, 0, stream>>>(feat, w1t, hp_part, W1b, W2b,
                                               Vk, Vb, el_arr, eden, pctx);
    k_finalize<<<Bsz * 4, 256, 0, stream>>>(el_arr, eden, pctx, ctx, wout);
}

// Round 6
// 315.347 us; speedup vs baseline: 1.1445x; 1.0356x over previous
//
#include <hip/hip_runtime.h>

#define Bsz 64
#define Lsz 4096
#define Dsz 512
#define Hsz 512
#define Usz 256
#define LT  32
#define NLB (Lsz / LT)          // 128 L-tiles per batch
#define TPB 16                  // tiles per block
#define NQB (NLB / TPB)         // 8 blocks per batch -> 512 blocks total
#define AW  520                 // LDS row stride (shorts): 1040B, 16B-aligned

typedef __attribute__((ext_vector_type(8))) short s8v;     // bf16x8 MFMA frag
typedef __attribute__((ext_vector_type(4))) float f4v;
typedef __attribute__((ext_vector_type(4))) unsigned short u16x4;

__device__ __forceinline__ unsigned short f2bf(float f) {
    unsigned int u = __float_as_uint(f);
    u += 0x7FFFu + ((u >> 16) & 1u);   // RNE
    return (unsigned short)(u >> 16);
}
__device__ __forceinline__ float bf2f(unsigned int lo16) {
    return __uint_as_float(lo16 << 16);
}
// barrier draining LDS only (NOT vmcnt) -> global loads stay in flight
__device__ __forceinline__ void barrier_lds() {
    asm volatile("s_waitcnt lgkmcnt(0)" ::: "memory");
    __builtin_amdgcn_s_barrier();
}

// ws layout
//   [0,     256K) : W1T bf16 [256][512]
//   [256K,  512K) : hp_part f32 [4][64][256]
//   [512K, 1536K) : el_arr f32 [64][4096]
//   [1536K,1568K) : eden f32 [64][128]
//   [1568K,2592K) : pctx f32 [64][8][512]

__global__ __launch_bounds__(256) void k_prep(const float* __restrict__ W1,
                                              const float* __restrict__ hidden,
                                              const float* __restrict__ W2,
                                              unsigned short* __restrict__ W1T,
                                              float* __restrict__ hp_part) {
    int blk = blockIdx.x, tid = threadIdx.x;
    if (blk < 512) {
        int e = blk * 256 + tid;          // coalesced over W1 [512][256]
        int k = e >> 8, u = e & 255;
        W1T[u * Dsz + k] = f2bf(W1[e]);
    } else {
        int idx = blk - 512;
        int kq = idx >> 6, b = idx & 63;  // K-quarter, batch
        const float* hrow = hidden + (size_t)b * Hsz + kq * 128;
        const float* w2p  = W2 + (size_t)(kq * 128) * Usz + tid;
        float a0 = 0.f, a1 = 0.f, a2 = 0.f, a3 = 0.f;
#pragma unroll 8
        for (int k = 0; k < 128; k += 4) {
            a0 = fmaf(hrow[k + 0], w2p[(size_t)(k + 0) * Usz], a0);
            a1 = fmaf(hrow[k + 1], w2p[(size_t)(k + 1) * Usz], a1);
            a2 = fmaf(hrow[k + 2], w2p[(size_t)(k + 2) * Usz], a2);
            a3 = fmaf(hrow[k + 3], w2p[(size_t)(k + 3) * Usz], a3);
        }
        hp_part[((size_t)kq * Bsz + b) * Usz + tid] = (a0 + a1) + (a2 + a3);
    }
}

// 512 blocks x 512 thr (8 waves, 2 blocks/CU). Block (b,q8): 16 tiles of 32 rows.
// Wave w owns U-cols [w*32, w*32+32).
__global__ __launch_bounds__(512, 4) void k_score_ctx(
    const float* __restrict__ feat, const unsigned short* __restrict__ W1T,
    const float* __restrict__ hp_part, const float* __restrict__ W1b,
    const float* __restrict__ W2b, const float* __restrict__ Vk,
    const float* __restrict__ Vb, float* __restrict__ el_arr,
    float* __restrict__ eden, float* __restrict__ pctx)
{
    __shared__ __align__(16) unsigned short A[LT][AW];   // 33.3 KiB
    __shared__ float hp[Usz], vv[Usz];
    __shared__ float spart[8][LT];
    __shared__ float el[LT];
    __shared__ float pc[2][Dsz];

    const int tid  = threadIdx.x;
    const int w    = tid >> 6;
    const int lane = tid & 63;
    const int lr   = lane & 15;
    const int lg   = lane >> 4;
    const int b    = blockIdx.x >> 3;
    const int q8   = blockIdx.x & 7;

    if (tid < Usz) {
        const float* hpb = hp_part + (size_t)b * Usz + tid;
        hp[tid] = (hpb[0] + hpb[Bsz * Usz]) + (hpb[2 * Bsz * Usz] + hpb[3 * Bsz * Usz])
                + W1b[tid] + W2b[tid];
        vv[tid] = Vk[tid];
    }

    const float* fbase = feat + ((size_t)b * Lsz + q8 * (TPB * LT)) * Dsz;
    const int srow = tid >> 7;              // 0..3
    const int sc4  = (tid & 127) * 4;       // float col

    // ---- prologue: stage tile 0 ----
    f4v st[8];
#pragma unroll
    for (int i = 0; i < 8; ++i)
        st[i] = *reinterpret_cast<const f4v*>(fbase + (size_t)(i * 4 + srow) * Dsz + sc4);
#pragma unroll
    for (int i = 0; i < 8; ++i) {
        int row = i * 4 + srow;
        u16x4 o = { f2bf(st[i].x), f2bf(st[i].y), f2bf(st[i].z), f2bf(st[i].w) };
        *reinterpret_cast<u16x4*>(&A[row][sc4]) = o;
    }
    barrier_lds();

    float c0 = 0.f, c1 = 0.f;
    const int qr = tid >> 8;                // 0..1 (row half)
    const int d0 = (tid & 255) * 2;
    const unsigned short* bp = W1T + (size_t)(w * 32 + lr) * Dsz + lg * 8;

#pragma unroll 1
    for (int t = 0; t < TPB; ++t) {
        f4v acc[2][2];
        acc[0][0] = (f4v){0.f, 0.f, 0.f, 0.f};
        acc[0][1] = (f4v){0.f, 0.f, 0.f, 0.f};
        acc[1][0] = (f4v){0.f, 0.f, 0.f, 0.f};
        acc[1][1] = (f4v){0.f, 0.f, 0.f, 0.f};

        // ---- GEMM in 4 B-groups of 8 frags (32 regs, reused) ----
#pragma unroll
        for (int g = 0; g < 4; ++g) {
            __builtin_amdgcn_sched_barrier(0);     // keep groups separate
            s8v bh[4][2];
#pragma unroll
            for (int k = 0; k < 4; ++k) {
                bh[k][0] = *reinterpret_cast<const s8v*>(bp + (g * 4 + k) * 32);
                bh[k][1] = *reinterpret_cast<const s8v*>(bp + 16 * Dsz + (g * 4 + k) * 32);
            }
            if (g == 3) {
                // issue next-tile feature loads AFTER all B loads:
                // g3's MFMA wait is vmcnt(8) -> st stays in flight to phase 8
                __builtin_amdgcn_sched_barrier(0);
                if (t < TPB - 1) {
                    const float* fn = fbase + (size_t)(t + 1) * LT * Dsz;
#pragma unroll
                    for (int i = 0; i < 8; ++i)
                        st[i] = *reinterpret_cast<const f4v*>(fn + (size_t)(i * 4 + srow) * Dsz + sc4);
                }
                __builtin_amdgcn_sched_barrier(0);
            }
#pragma unroll
            for (int k = 0; k < 4; ++k) {
                const int kof = (g * 4 + k) * 32 + lg * 8;
#pragma unroll
                for (int mf = 0; mf < 2; ++mf) {
                    const int row = mf * 16 + lr;
                    s8v a = *reinterpret_cast<const s8v*>(&A[row][kof]);
                    acc[mf][0] = __builtin_amdgcn_mfma_f32_16x16x32_bf16(a, bh[k][0], acc[mf][0], 0, 0, 0);
                    acc[mf][1] = __builtin_amdgcn_mfma_f32_16x16x32_bf16(a, bh[k][1], acc[mf][1], 0, 0, 0);
                }
            }
        }

        // ---- epilogue: per-row sum of tanh(x)*V over this wave's 32 cols ----
        {
            float rs[2][4];
#pragma unroll
            for (int mf = 0; mf < 2; ++mf)
#pragma unroll
                for (int r = 0; r < 4; ++r) rs[mf][r] = 0.f;
#pragma unroll
            for (int mf = 0; mf < 2; ++mf)
#pragma unroll
                for (int nf = 0; nf < 2; ++nf) {
                    int col = w * 32 + nf * 16 + lr;
                    float hpv = hp[col], vvv = vv[col];
#pragma unroll
                    for (int r = 0; r < 4; ++r) {
                        float x = acc[mf][nf][r] + hpv;
                        float e = __expf(2.f * x);
                        rs[mf][r] = fmaf(1.f - 2.f / (e + 1.f), vvv, rs[mf][r]);
                    }
                }
#pragma unroll
            for (int off = 1; off < 16; off <<= 1)
#pragma unroll
                for (int mf = 0; mf < 2; ++mf)
#pragma unroll
                    for (int r = 0; r < 4; ++r)
                        rs[mf][r] += __shfl_xor(rs[mf][r], off, 64);
            if (lr == 0)
#pragma unroll
                for (int mf = 0; mf < 2; ++mf)
#pragma unroll
                    for (int r = 0; r < 4; ++r)
                        spart[w][mf * 16 + lg * 4 + r] = rs[mf][r];
        }
        barrier_lds();

        // ---- scores -> exp -> per-tile denominator (32 lanes of wave 0) ----
        if (tid < LT) {
            float s = Vb[0];
#pragma unroll
            for (int ww = 0; ww < 8; ++ww) s += spart[ww][tid];
            float e = __expf(s);
            el[tid] = e;
            el_arr[(size_t)b * Lsz + (q8 * TPB + t) * LT + tid] = e;
            float es = e;
#pragma unroll
            for (int off = 1; off < 32; off <<= 1) es += __shfl_xor(es, off, 64);
            if (tid == 0) eden[b * NLB + q8 * TPB + t] = es;
        }
        barrier_lds();

        // ---- context accumulate from current LDS tile ----
#pragma unroll
        for (int li = 0; li < 16; ++li) {
            int l = qr * 16 + li;
            unsigned int pk = *reinterpret_cast<const unsigned int*>(&A[l][d0]);
            float e = el[l];
            c0 = fmaf(e, bf2f(pk & 0xFFFFu), c0);
            c1 = fmaf(e, bf2f(pk >> 16), c1);
        }
        barrier_lds();

        // ---- write staged regs -> LDS (auto vmcnt wait lands here, covered) ----
        if (t < TPB - 1) {
#pragma unroll
            for (int i = 0; i < 8; ++i) {
                int row = i * 4 + srow;
                u16x4 o = { f2bf(st[i].x), f2bf(st[i].y), f2bf(st[i].z), f2bf(st[i].w) };
                *reinterpret_cast<u16x4*>(&A[row][sc4]) = o;
            }
        }
        barrier_lds();
    }

    // ---- final partial-context write ----
    pc[qr][d0]     = c0;
    pc[qr][d0 + 1] = c1;
    barrier_lds();
    pctx[((size_t)b * NQB + q8) * Dsz + tid] = pc[0][tid] + pc[1][tid];
}

__global__ __launch_bounds__(256) void k_finalize(const float* __restrict__ el_arr,
                                                  const float* __restrict__ eden,
                                                  const float* __restrict__ pctx,
                                                  float* __restrict__ ctx,
                                                  float* __restrict__ wout) {
    int blk = blockIdx.x, tid = threadIdx.x;
    int b = blk >> 2, dq = blk & 3;
    float s = eden[b * NLB + (tid & 63)] + eden[b * NLB + 64 + (tid & 63)];
#pragma unroll
    for (int off = 1; off < 64; off <<= 1) s += __shfl_xor(s, off, 64);
    float inv = 1.f / s;

    if (tid < 128) {
        int d = dq * 128 + tid;
        float c = 0.f;
#pragma unroll
        for (int p = 0; p < NQB; ++p) c += pctx[((size_t)b * NQB + p) * Dsz + d];
        ctx[(size_t)b * Dsz + d] = c * inv;
    }
#pragma unroll
    for (int i = 0; i < 4; ++i) {
        size_t idx = (size_t)b * Lsz + dq * 1024 + i * 256 + tid;
        wout[idx] = el_arr[idx] * inv;
    }
}

extern "C" void kernel_launch(void* const* d_in, const int* in_sizes, int n_in,
                              void* d_out, int out_size, void* d_ws, size_t ws_size,
                              hipStream_t stream) {
    const float* feat   = (const float*)d_in[0];
    const float* hidden = (const float*)d_in[1];
    const float* W1     = (const float*)d_in[2];
    const float* W1b    = (const float*)d_in[3];
    const float* W2     = (const float*)d_in[4];
    const float* W2b    = (const float*)d_in[5];
    const float* Vk     = (const float*)d_in[6];
    const float* Vb     = (const float*)d_in[7];

    unsigned short* w1t = (unsigned short*)d_ws;
    float* hp_part = (float*)((char*)d_ws + 256 * 1024);
    float* el_arr  = (float*)((char*)d_ws + 512 * 1024);
    float* eden    = (float*)((char*)d_ws + 1536 * 1024);
    float* pctx    = (float*)((char*)d_ws + 1568 * 1024);

    float* ctx  = (float*)d_out;              // [64, 512]
    float* wout = ctx + Bsz * Dsz;            // [64, 4096, 1]

    k_prep<<<768, 256, 0, stream>>>(W1, hidden, W2, w1t, hp_part);
    k_score_ctx<<<Bsz * NQB, 512, 0, stream>>>(feat, w1t, hp_part, W1b, W2b,
                                               Vk, Vb, el_arr, eden, pctx);
    k_finalize<<<Bsz * 4, 256, 0, stream>>>(el_arr, eden, pctx, ctx, wout);
}

// Round 7
// 289.576 us; speedup vs baseline: 1.2464x; 1.0890x over previous
//
#include <hip/hip_runtime.h>

#define Bsz 64
#define Lsz 4096
#define Dsz 512
#define Hsz 512
#define Usz 256
#define LT  32
#define NLB (Lsz / LT)          // 128 L-tiles per batch
#define AW  520                 // LDS row stride (shorts): 1040B, 16B-aligned

typedef __attribute__((ext_vector_type(8))) short s8v;     // bf16x8 MFMA frag
typedef __attribute__((ext_vector_type(4))) float f4v;
typedef __attribute__((ext_vector_type(4))) unsigned short u16x4;

__device__ __forceinline__ unsigned short f2bf(float f) {
    unsigned int u = __float_as_uint(f);
    u += 0x7FFFu + ((u >> 16) & 1u);   // RNE
    return (unsigned short)(u >> 16);
}
__device__ __forceinline__ float bf2f(unsigned int lo16) {
    return __uint_as_float(lo16 << 16);
}

// ws layout
//   [0,     256K)      : W1T bf16 [256][512]
//   [256K,  512K)      : hp_part f32 [4][64][256]
//   [512K, 1536K)      : el_arr f32 [64][4096]
//   [1536K, +256B)     : den f32 [64]
//   [1536K+256, +128K) : ctx_acc f32 [64][512]

__global__ __launch_bounds__(256) void k_prep(const float* __restrict__ W1,
                                              const float* __restrict__ hidden,
                                              const float* __restrict__ W2,
                                              unsigned short* __restrict__ W1T,
                                              float* __restrict__ hp_part) {
    int blk = blockIdx.x, tid = threadIdx.x;
    if (blk < 512) {
        int e = blk * 256 + tid;          // coalesced over W1 [512][256]
        int k = e >> 8, u = e & 255;
        W1T[u * Dsz + k] = f2bf(W1[e]);
    } else {
        int idx = blk - 512;
        int kq = idx >> 6, b = idx & 63;  // K-quarter, batch
        const float* hrow = hidden + (size_t)b * Hsz + kq * 128;
        const float* w2p  = W2 + (size_t)(kq * 128) * Usz + tid;
        float a0 = 0.f, a1 = 0.f, a2 = 0.f, a3 = 0.f;
#pragma unroll 8
        for (int k = 0; k < 128; k += 4) {
            a0 = fmaf(hrow[k + 0], w2p[(size_t)(k + 0) * Usz], a0);
            a1 = fmaf(hrow[k + 1], w2p[(size_t)(k + 1) * Usz], a1);
            a2 = fmaf(hrow[k + 2], w2p[(size_t)(k + 2) * Usz], a2);
            a3 = fmaf(hrow[k + 3], w2p[(size_t)(k + 3) * Usz], a3);
        }
        hp_part[((size_t)kq * Bsz + b) * Usz + tid] = (a0 + a1) + (a2 + a3);
    }
}

// 8192 blocks x 512 thr (8 waves). 4 blocks/CU (launch_bounds(512,8) -> <=64 VGPR).
// Block (b, lb): one 32-row tile. Wave w owns U-cols [w*32, w*32+32) (U-only split:
// each W1T byte read once per tile -> B-L2 traffic = 2 GiB total, under ceiling).
__global__ __launch_bounds__(512, 8) void k_score_ctx(
    const float* __restrict__ feat, const unsigned short* __restrict__ W1T,
    const float* __restrict__ hp_part, const float* __restrict__ W1b,
    const float* __restrict__ W2b, const float* __restrict__ Vk,
    const float* __restrict__ Vb, float* __restrict__ el_arr,
    float* __restrict__ den, float* __restrict__ ctx_acc)
{
    __shared__ __align__(16) unsigned short A[LT][AW];   // 33.3 KiB
    __shared__ float hp[Usz], vv[Usz];
    __shared__ float spart[8][LT];
    __shared__ float el[LT];

    const int tid  = threadIdx.x;
    const int w    = tid >> 6;
    const int lane = tid & 63;
    const int lr   = lane & 15;
    const int lg   = lane >> 4;
    const int b    = blockIdx.x >> 7;
    const int lb   = blockIdx.x & 127;
    const int l0   = lb * LT;

    if (tid < Usz) {
        const float* hpb = hp_part + (size_t)b * Usz + tid;
        hp[tid] = (hpb[0] + hpb[Bsz * Usz]) + (hpb[2 * Bsz * Usz] + hpb[3 * Bsz * Usz])
                + W1b[tid] + W2b[tid];
        vv[tid] = Vk[tid];
    }

    // ---- stage 32x512 fp32 -> bf16 (transient regs only) ----
    {
        const float* fb = feat + ((size_t)b * Lsz + l0) * Dsz;
        const int srow = tid >> 7;          // 0..3
        const int sc4  = (tid & 127) * 4;
#pragma unroll 2
        for (int i = 0; i < 8; ++i) {
            int row = i * 4 + srow;
            f4v v = *reinterpret_cast<const f4v*>(fb + (size_t)row * Dsz + sc4);
            u16x4 o = { f2bf(v.x), f2bf(v.y), f2bf(v.z), f2bf(v.w) };
            *reinterpret_cast<u16x4*>(&A[row][sc4]) = o;
        }
    }
    __syncthreads();

    // ---- GEMM: 32 rows x this wave's 32 cols x K=512 ----
    const unsigned short* bp = W1T + (size_t)(w * 32 + lr) * Dsz + lg * 8;
    f4v acc[2][2];
    acc[0][0] = (f4v){0.f, 0.f, 0.f, 0.f};
    acc[0][1] = (f4v){0.f, 0.f, 0.f, 0.f};
    acc[1][0] = (f4v){0.f, 0.f, 0.f, 0.f};
    acc[1][1] = (f4v){0.f, 0.f, 0.f, 0.f};
#pragma unroll 2
    for (int ks = 0; ks < 16; ++ks) {
        s8v b0 = *reinterpret_cast<const s8v*>(bp + ks * 32);
        s8v b1 = *reinterpret_cast<const s8v*>(bp + 16 * Dsz + ks * 32);
        const int kof = ks * 32 + lg * 8;
        s8v a0 = *reinterpret_cast<const s8v*>(&A[lr][kof]);
        s8v a1 = *reinterpret_cast<const s8v*>(&A[16 + lr][kof]);
        acc[0][0] = __builtin_amdgcn_mfma_f32_16x16x32_bf16(a0, b0, acc[0][0], 0, 0, 0);
        acc[0][1] = __builtin_amdgcn_mfma_f32_16x16x32_bf16(a0, b1, acc[0][1], 0, 0, 0);
        acc[1][0] = __builtin_amdgcn_mfma_f32_16x16x32_bf16(a1, b0, acc[1][0], 0, 0, 0);
        acc[1][1] = __builtin_amdgcn_mfma_f32_16x16x32_bf16(a1, b1, acc[1][1], 0, 0, 0);
    }

    // ---- epilogue: per-row sum of tanh(x)*V over this wave's 32 cols ----
    {
        float rs[2][4];
#pragma unroll
        for (int mf = 0; mf < 2; ++mf)
#pragma unroll
            for (int r = 0; r < 4; ++r) rs[mf][r] = 0.f;
#pragma unroll
        for (int mf = 0; mf < 2; ++mf)
#pragma unroll
            for (int nf = 0; nf < 2; ++nf) {
                int col = w * 32 + nf * 16 + lr;
                float hpv = hp[col], vvv = vv[col];
#pragma unroll
                for (int r = 0; r < 4; ++r) {
                    float x = acc[mf][nf][r] + hpv;
                    float e = __expf(2.f * x);
                    rs[mf][r] = fmaf(1.f - 2.f / (e + 1.f), vvv, rs[mf][r]);
                }
            }
#pragma unroll
        for (int off = 1; off < 16; off <<= 1)
#pragma unroll
            for (int mf = 0; mf < 2; ++mf)
#pragma unroll
                for (int r = 0; r < 4; ++r)
                    rs[mf][r] += __shfl_xor(rs[mf][r], off, 64);
        if (lr == 0)
#pragma unroll
            for (int mf = 0; mf < 2; ++mf)
#pragma unroll
                for (int r = 0; r < 4; ++r)
                    spart[w][mf * 16 + lg * 4 + r] = rs[mf][r];
    }
    __syncthreads();

    // ---- scores -> exp -> denominator (lanes 0-31 of wave 0) ----
    if (tid < LT) {
        float s = Vb[0];
#pragma unroll
        for (int ww = 0; ww < 8; ++ww) s += spart[ww][tid];
        float e = __expf(s);
        el[tid] = e;
        el_arr[(size_t)b * Lsz + l0 + tid] = e;
        float es = e;
#pragma unroll
        for (int off = 1; off < 32; off <<= 1) es += __shfl_xor(es, off, 64);
        if (tid == 0) atomicAdd(&den[b], es);
    }
    __syncthreads();

    // ---- context: thread d accumulates over the 32 rows, one atomic ----
    {
        float c = 0.f;
#pragma unroll
        for (int l = 0; l < LT; ++l)
            c = fmaf(el[l], bf2f((unsigned int)A[l][tid]), c);
        atomicAdd(&ctx_acc[b * Dsz + tid], c);
    }
}

__global__ __launch_bounds__(256) void k_finalize(const float* __restrict__ el_arr,
                                                  const float* __restrict__ den,
                                                  const float* __restrict__ ctx_acc,
                                                  float* __restrict__ ctx,
                                                  float* __restrict__ wout) {
    int b = blockIdx.x, tid = threadIdx.x;
    float inv = 1.f / den[b];
    ctx[(size_t)b * Dsz + tid]       = ctx_acc[b * Dsz + tid] * inv;
    ctx[(size_t)b * Dsz + 256 + tid] = ctx_acc[b * Dsz + 256 + tid] * inv;
#pragma unroll
    for (int i = 0; i < Lsz / 256; ++i) {
        size_t idx = (size_t)b * Lsz + i * 256 + tid;
        wout[idx] = el_arr[idx] * inv;
    }
}

extern "C" void kernel_launch(void* const* d_in, const int* in_sizes, int n_in,
                              void* d_out, int out_size, void* d_ws, size_t ws_size,
                              hipStream_t stream) {
    const float* feat   = (const float*)d_in[0];
    const float* hidden = (const float*)d_in[1];
    const float* W1     = (const float*)d_in[2];
    const float* W1b    = (const float*)d_in[3];
    const float* W2     = (const float*)d_in[4];
    const float* W2b    = (const float*)d_in[5];
    const float* Vk     = (const float*)d_in[6];
    const float* Vb     = (const float*)d_in[7];

    unsigned short* w1t = (unsigned short*)d_ws;
    float* hp_part = (float*)((char*)d_ws + 256 * 1024);
    float* el_arr  = (float*)((char*)d_ws + 512 * 1024);
    float* den     = (float*)((char*)d_ws + 1536 * 1024);
    float* ctx_acc = (float*)((char*)d_ws + 1536 * 1024 + 256);

    float* ctx  = (float*)d_out;              // [64, 512]
    float* wout = ctx + Bsz * Dsz;            // [64, 4096, 1]

    // zero den + ctx_acc (contiguous 256B + 128KiB)
    hipMemsetAsync(den, 0, 256 + Bsz * Dsz * sizeof(float), stream);
    k_prep<<<768, 256, 0, stream>>>(W1, hidden, W2, w1t, hp_part);
    k_score_ctx<<<Bsz * NLB, 512, 0, stream>>>(feat, w1t, hp_part, W1b, W2b,
                                               Vk, Vb, el_arr, den, ctx_acc);
    k_finalize<<<Bsz, 256, 0, stream>>>(el_arr, den, ctx_acc, ctx, wout);
}

// Round 8
// 206.666 us; speedup vs baseline: 1.7464x; 1.4012x over previous
//
#include <hip/hip_runtime.h>

#define Bsz 64
#define Lsz 4096
#define Dsz 512
#define Hsz 512
#define Usz 256
#define LT  64
#define NLB (Lsz / LT)          // 64 L-tiles per batch -> 4096 blocks
#define AW  520                 // LDS row stride (shorts): 1040B, 16B-aligned

typedef __attribute__((ext_vector_type(8))) short s8v;     // bf16x8 MFMA frag
typedef __attribute__((ext_vector_type(4))) float f4v;
typedef __attribute__((ext_vector_type(8))) unsigned short u16x8;

__device__ __forceinline__ unsigned short f2bf(float f) {
    unsigned int u = __float_as_uint(f);
    u += 0x7FFFu + ((u >> 16) & 1u);   // RNE
    return (unsigned short)(u >> 16);
}
__device__ __forceinline__ float bf2f(unsigned int lo16) {
    return __uint_as_float(lo16 << 16);
}

// ws layout
//   [0,     256K)      : W1T bf16 [256][512]
//   [256K,  512K)      : hp_part f32 [4][64][256]
//   [512K, 1536K)      : el_arr f32 [64][4096]
//   [1536K, +256B)     : den f32 [64]
//   [1536K+256, +128K) : ctx_acc f32 [64][512]

__global__ __launch_bounds__(256) void k_prep(const float* __restrict__ W1,
                                              const float* __restrict__ hidden,
                                              const float* __restrict__ W2,
                                              unsigned short* __restrict__ W1T,
                                              float* __restrict__ hp_part) {
    int blk = blockIdx.x, tid = threadIdx.x;
    if (blk < 512) {
        int e = blk * 256 + tid;          // coalesced over W1 [512][256]
        int k = e >> 8, u = e & 255;
        W1T[u * Dsz + k] = f2bf(W1[e]);
    } else {
        int idx = blk - 512;
        int kq = idx >> 6, b = idx & 63;  // K-quarter, batch
        const float* hrow = hidden + (size_t)b * Hsz + kq * 128;
        const float* w2p  = W2 + (size_t)(kq * 128) * Usz + tid;
        float a0 = 0.f, a1 = 0.f, a2 = 0.f, a3 = 0.f;
#pragma unroll 8
        for (int k = 0; k < 128; k += 4) {
            a0 = fmaf(hrow[k + 0], w2p[(size_t)(k + 0) * Usz], a0);
            a1 = fmaf(hrow[k + 1], w2p[(size_t)(k + 1) * Usz], a1);
            a2 = fmaf(hrow[k + 2], w2p[(size_t)(k + 2) * Usz], a2);
            a3 = fmaf(hrow[k + 3], w2p[(size_t)(k + 3) * Usz], a3);
        }
        hp_part[((size_t)kq * Bsz + b) * Usz + tid] = (a0 + a1) + (a2 + a3);
    }
}

// 4096 blocks x 512 thr (8 waves), 2 blocks/CU. Block (b,lb): one 64-row tile.
// Wave w owns U-cols [w*32, w*32+32). B-frags: depth-2 ping-pong prefetch.
__global__ __launch_bounds__(512, 4) void k_score_ctx(
    const float* __restrict__ feat, const unsigned short* __restrict__ W1T,
    const float* __restrict__ hp_part, const float* __restrict__ W1b,
    const float* __restrict__ W2b, const float* __restrict__ Vk,
    const float* __restrict__ Vb, float* __restrict__ el_arr,
    float* __restrict__ den, float* __restrict__ ctx_acc)
{
    __shared__ __align__(16) unsigned short A[LT][AW];   // 66.6 KiB
    __shared__ float hp[Usz], vv[Usz];
    __shared__ float spart[8][LT];
    __shared__ float el[LT];

    const int tid  = threadIdx.x;
    const int w    = tid >> 6;
    const int lane = tid & 63;
    const int lr   = lane & 15;
    const int lg   = lane >> 4;
    const int b    = blockIdx.x >> 6;
    const int lb   = blockIdx.x & 63;
    const int l0   = lb * LT;

    if (tid < Usz) {
        const float* hpb = hp_part + (size_t)b * Usz + tid;
        hp[tid] = (hpb[0] + hpb[Bsz * Usz]) + (hpb[2 * Bsz * Usz] + hpb[3 * Bsz * Usz])
                + W1b[tid] + W2b[tid];
        vv[tid] = Vk[tid];
    }

    // ---- stage 64x512 fp32 -> bf16 (b128 LDS writes; transient regs) ----
    {
        const float* fb = feat + ((size_t)b * Lsz + l0) * Dsz;
        const int c8 = (tid & 63) * 8;      // float/short col (16B store granule)
#pragma unroll 2
        for (int i = 0; i < 8; ++i) {
            int row = i * 8 + w;
            const float* rp = fb + (size_t)row * Dsz + c8;
            f4v v0 = *reinterpret_cast<const f4v*>(rp);
            f4v v1 = *reinterpret_cast<const f4v*>(rp + 4);
            u16x8 o = { f2bf(v0.x), f2bf(v0.y), f2bf(v0.z), f2bf(v0.w),
                        f2bf(v1.x), f2bf(v1.y), f2bf(v1.z), f2bf(v1.w) };
            *reinterpret_cast<u16x8*>(&A[row][c8]) = o;
        }
    }
    __syncthreads();

    // ---- GEMM: 64 rows x this wave's 32 cols x K=512, ping-pong B prefetch ----
    const unsigned short* bp = W1T + (size_t)(w * 32 + lr) * Dsz + lg * 8;
    f4v acc[4][2];
#pragma unroll
    for (int mf = 0; mf < 4; ++mf) {
        acc[mf][0] = (f4v){0.f, 0.f, 0.f, 0.f};
        acc[mf][1] = (f4v){0.f, 0.f, 0.f, 0.f};
    }

    s8v b0[2], b1[2];
    b0[0] = *reinterpret_cast<const s8v*>(bp);
    b0[1] = *reinterpret_cast<const s8v*>(bp + 16 * Dsz);
    b1[0] = *reinterpret_cast<const s8v*>(bp + 32);
    b1[1] = *reinterpret_cast<const s8v*>(bp + 16 * Dsz + 32);

#pragma unroll 1
    for (int ks = 0; ks < 16; ks += 2) {
        s8v n0[2], n1[2];
        if (ks < 14) {
            n0[0] = *reinterpret_cast<const s8v*>(bp + (ks + 2) * 32);
            n0[1] = *reinterpret_cast<const s8v*>(bp + 16 * Dsz + (ks + 2) * 32);
            n1[0] = *reinterpret_cast<const s8v*>(bp + (ks + 3) * 32);
            n1[1] = *reinterpret_cast<const s8v*>(bp + 16 * Dsz + (ks + 3) * 32);
        }
        __builtin_amdgcn_sched_barrier(0);
        {
            const int kof = ks * 32 + lg * 8;
#pragma unroll
            for (int mf = 0; mf < 4; ++mf) {
                s8v a = *reinterpret_cast<const s8v*>(&A[mf * 16 + lr][kof]);
                acc[mf][0] = __builtin_amdgcn_mfma_f32_16x16x32_bf16(a, b0[0], acc[mf][0], 0, 0, 0);
                acc[mf][1] = __builtin_amdgcn_mfma_f32_16x16x32_bf16(a, b0[1], acc[mf][1], 0, 0, 0);
            }
        }
        {
            const int kof = (ks + 1) * 32 + lg * 8;
#pragma unroll
            for (int mf = 0; mf < 4; ++mf) {
                s8v a = *reinterpret_cast<const s8v*>(&A[mf * 16 + lr][kof]);
                acc[mf][0] = __builtin_amdgcn_mfma_f32_16x16x32_bf16(a, b1[0], acc[mf][0], 0, 0, 0);
                acc[mf][1] = __builtin_amdgcn_mfma_f32_16x16x32_bf16(a, b1[1], acc[mf][1], 0, 0, 0);
            }
        }
        b0[0] = n0[0]; b0[1] = n0[1];
        b1[0] = n1[0]; b1[1] = n1[1];
    }

    // ---- epilogue: per-row sum of tanh(x)*V over this wave's 32 cols ----
    {
        float rs[4][4];
#pragma unroll
        for (int mf = 0; mf < 4; ++mf)
#pragma unroll
            for (int r = 0; r < 4; ++r) rs[mf][r] = 0.f;
#pragma unroll
        for (int mf = 0; mf < 4; ++mf)
#pragma unroll
            for (int nf = 0; nf < 2; ++nf) {
                int col = w * 32 + nf * 16 + lr;
                float hpv = hp[col], vvv = vv[col];
#pragma unroll
                for (int r = 0; r < 4; ++r) {
                    float x = acc[mf][nf][r] + hpv;
                    float e = __expf(2.f * x);
                    rs[mf][r] = fmaf(1.f - 2.f / (e + 1.f), vvv, rs[mf][r]);
                }
            }
#pragma unroll
        for (int off = 1; off < 16; off <<= 1)
#pragma unroll
            for (int mf = 0; mf < 4; ++mf)
#pragma unroll
                for (int r = 0; r < 4; ++r)
                    rs[mf][r] += __shfl_xor(rs[mf][r], off, 64);
        if (lr == 0)
#pragma unroll
            for (int mf = 0; mf < 4; ++mf)
#pragma unroll
                for (int r = 0; r < 4; ++r)
                    spart[w][mf * 16 + lg * 4 + r] = rs[mf][r];
    }
    __syncthreads();

    // ---- scores -> exp -> denominator (wave 0) ----
    if (tid < LT) {
        float s = Vb[0];
#pragma unroll
        for (int ww = 0; ww < 8; ++ww) s += spart[ww][tid];
        float e = __expf(s);
        el[tid] = e;
        el_arr[(size_t)b * Lsz + l0 + tid] = e;
        float es = e;
#pragma unroll
        for (int off = 1; off < 64; off <<= 1) es += __shfl_xor(es, off, 64);
        if (tid == 0) atomicAdd(&den[b], es);
    }
    __syncthreads();

    // ---- context: thread d accumulates over the 64 rows, one atomic ----
    {
        float c = 0.f;
#pragma unroll 8
        for (int l = 0; l < LT; ++l)
            c = fmaf(el[l], bf2f((unsigned int)A[l][tid]), c);
        atomicAdd(&ctx_acc[b * Dsz + tid], c);
    }
}

__global__ __launch_bounds__(256) void k_finalize(const float* __restrict__ el_arr,
                                                  const float* __restrict__ den,
                                                  const float* __restrict__ ctx_acc,
                                                  float* __restrict__ ctx,
                                                  float* __restrict__ wout) {
    int b = blockIdx.x, tid = threadIdx.x;
    float inv = 1.f / den[b];
    ctx[(size_t)b * Dsz + tid]       = ctx_acc[b * Dsz + tid] * inv;
    ctx[(size_t)b * Dsz + 256 + tid] = ctx_acc[b * Dsz + 256 + tid] * inv;
#pragma unroll
    for (int i = 0; i < Lsz / 256; ++i) {
        size_t idx = (size_t)b * Lsz + i * 256 + tid;
        wout[idx] = el_arr[idx] * inv;
    }
}

extern "C" void kernel_launch(void* const* d_in, const int* in_sizes, int n_in,
                              void* d_out, int out_size, void* d_ws, size_t ws_size,
                              hipStream_t stream) {
    const float* feat   = (const float*)d_in[0];
    const float* hidden = (const float*)d_in[1];
    const float* W1     = (const float*)d_in[2];
    const float* W1b    = (const float*)d_in[3];
    const float* W2     = (const float*)d_in[4];
    const float* W2b    = (const float*)d_in[5];
    const float* Vk     = (const float*)d_in[6];
    const float* Vb     = (const float*)d_in[7];

    unsigned short* w1t = (unsigned short*)d_ws;
    float* hp_part = (float*)((char*)d_ws + 256 * 1024);
    float* el_arr  = (float*)((char*)d_ws + 512 * 1024);
    float* den     = (float*)((char*)d_ws + 1536 * 1024);
    float* ctx_acc = (float*)((char*)d_ws + 1536 * 1024 + 256);

    float* ctx  = (float*)d_out;              // [64, 512]
    float* wout = ctx + Bsz * Dsz;            // [64, 4096, 1]

    // zero den + ctx_acc (contiguous 256B + 128KiB)
    hipMemsetAsync(den, 0, 256 + Bsz * Dsz * sizeof(float), stream);
    k_prep<<<768, 256, 0, stream>>>(W1, hidden, W2, w1t, hp_part);
    k_score_ctx<<<Bsz * NLB, 512, 0, stream>>>(feat, w1t, hp_part, W1b, W2b,
                                               Vk, Vb, el_arr, den, ctx_acc);
    k_finalize<<<Bsz, 256, 0, stream>>>(el_arr, den, ctx_acc, ctx, wout);
}

// Round 9
// 202.098 us; speedup vs baseline: 1.7859x; 1.0226x over previous
//
#include <hip/hip_runtime.h>

#define Bsz 64
#define Lsz 4096
#define Dsz 512
#define Hsz 512
#define Usz 256
#define LT  64
#define NLB (Lsz / LT)          // 64 L-tiles per batch -> 4096 blocks
#define AW  520                 // LDS row stride (shorts): 1040B, 16B-aligned

typedef __attribute__((ext_vector_type(8))) short s8v;     // bf16x8 MFMA frag
typedef __attribute__((ext_vector_type(4))) float f4v;
typedef __attribute__((ext_vector_type(8))) unsigned short u16x8;

__device__ __forceinline__ unsigned short f2bf(float f) {
    unsigned int u = __float_as_uint(f);
    u += 0x7FFFu + ((u >> 16) & 1u);   // RNE
    return (unsigned short)(u >> 16);
}
__device__ __forceinline__ float bf2f(unsigned int lo16) {
    return __uint_as_float(lo16 << 16);
}

// ws layout
//   [0,     256K)      : W1T bf16 [256][512]
//   [256K,  512K)      : hp_part f32 [4][64][256]
//   [512K, 1536K)      : el_arr f32 [64][4096]
//   [1536K, +256B)     : den f32 [64]
//   [1536K+256, +128K) : ctx_acc f32 [64][512]

// blocks 0..511: W1->W1T transpose+cast. 512..767: hproj split-K. 768..831: zero acc.
__global__ __launch_bounds__(256) void k_prep(const float* __restrict__ W1,
                                              const float* __restrict__ hidden,
                                              const float* __restrict__ W2,
                                              unsigned short* __restrict__ W1T,
                                              float* __restrict__ hp_part,
                                              float* __restrict__ den,
                                              float* __restrict__ ctx_acc) {
    int blk = blockIdx.x, tid = threadIdx.x;
    if (blk < 512) {
        int e = blk * 256 + tid;          // coalesced over W1 [512][256]
        int k = e >> 8, u = e & 255;
        W1T[u * Dsz + k] = f2bf(W1[e]);
    } else if (blk < 768) {
        int idx = blk - 512;
        int kq = idx >> 6, b = idx & 63;  // K-quarter, batch
        const float* hrow = hidden + (size_t)b * Hsz + kq * 128;
        const float* w2p  = W2 + (size_t)(kq * 128) * Usz + tid;
        float a0 = 0.f, a1 = 0.f, a2 = 0.f, a3 = 0.f;
#pragma unroll 8
        for (int k = 0; k < 128; k += 4) {
            a0 = fmaf(hrow[k + 0], w2p[(size_t)(k + 0) * Usz], a0);
            a1 = fmaf(hrow[k + 1], w2p[(size_t)(k + 1) * Usz], a1);
            a2 = fmaf(hrow[k + 2], w2p[(size_t)(k + 2) * Usz], a2);
            a3 = fmaf(hrow[k + 3], w2p[(size_t)(k + 3) * Usz], a3);
        }
        hp_part[((size_t)kq * Bsz + b) * Usz + tid] = (a0 + a1) + (a2 + a3);
    } else {
        int b = blk - 768;
        if (tid == 0) den[b] = 0.f;
        ctx_acc[b * Dsz + tid] = 0.f;
        ctx_acc[b * Dsz + 256 + tid] = 0.f;
    }
}

// 4096 blocks x 512 thr (8 waves), 2 blocks/CU. Block (b,lb): one 64-row tile.
// Wave w owns U-cols [w*32, w*32+32). B-frags: depth-4 rolling prefetch.
__global__ __launch_bounds__(512, 4) void k_score_ctx(
    const float* __restrict__ feat, const unsigned short* __restrict__ W1T,
    const float* __restrict__ hp_part, const float* __restrict__ W1b,
    const float* __restrict__ W2b, const float* __restrict__ Vk,
    const float* __restrict__ Vb, float* __restrict__ el_arr,
    float* __restrict__ den, float* __restrict__ ctx_acc)
{
    __shared__ __align__(16) unsigned short A[LT][AW];   // 65 KiB
    __shared__ float hp[Usz], vv[Usz];
    __shared__ float spart[8][LT];
    __shared__ float el[LT];
    __shared__ float pc[2][Dsz];

    const int tid  = threadIdx.x;
    const int w    = tid >> 6;
    const int lane = tid & 63;
    const int lr   = lane & 15;
    const int lg   = lane >> 4;
    const int b    = blockIdx.x >> 6;
    const int lb   = blockIdx.x & 63;
    const int l0   = lb * LT;

    if (tid < Usz) {
        const float* hpb = hp_part + (size_t)b * Usz + tid;
        hp[tid] = (hpb[0] + hpb[Bsz * Usz]) + (hpb[2 * Bsz * Usz] + hpb[3 * Bsz * Usz])
                + W1b[tid] + W2b[tid];
        vv[tid] = Vk[tid];
    }

    // ---- stage 64x512 fp32 -> bf16 (b128 LDS writes; transient regs) ----
    {
        const float* fb = feat + ((size_t)b * Lsz + l0) * Dsz;
        const int c8 = (tid & 63) * 8;      // short col (16B store granule)
#pragma unroll 2
        for (int i = 0; i < 8; ++i) {
            int row = i * 8 + w;
            const float* rp = fb + (size_t)row * Dsz + c8;
            f4v v0 = *reinterpret_cast<const f4v*>(rp);
            f4v v1 = *reinterpret_cast<const f4v*>(rp + 4);
            u16x8 o = { f2bf(v0.x), f2bf(v0.y), f2bf(v0.z), f2bf(v0.w),
                        f2bf(v1.x), f2bf(v1.y), f2bf(v1.z), f2bf(v1.w) };
            *reinterpret_cast<u16x8*>(&A[row][c8]) = o;
        }
    }
    __syncthreads();

    // ---- GEMM: 64 rows x this wave's 32 cols x K=512, depth-4 B prefetch ----
    const unsigned short* bp0 = W1T + (size_t)(w * 32 + lr) * Dsz + lg * 8;
    const unsigned short* bp1 = bp0 + 16 * Dsz;
    f4v acc[4][2];
#pragma unroll
    for (int mf = 0; mf < 4; ++mf) {
        acc[mf][0] = (f4v){0.f, 0.f, 0.f, 0.f};
        acc[mf][1] = (f4v){0.f, 0.f, 0.f, 0.f};
    }

    s8v bq[4][2];
#pragma unroll
    for (int i = 0; i < 4; ++i) {
        bq[i][0] = *reinterpret_cast<const s8v*>(bp0 + i * 32);
        bq[i][1] = *reinterpret_cast<const s8v*>(bp1 + i * 32);
    }

#pragma unroll
    for (int ks = 0; ks < 16; ++ks) {
        s8v c0 = bq[ks & 3][0];
        s8v c1 = bq[ks & 3][1];
        if (ks < 12) {
            bq[ks & 3][0] = *reinterpret_cast<const s8v*>(bp0 + (ks + 4) * 32);
            bq[ks & 3][1] = *reinterpret_cast<const s8v*>(bp1 + (ks + 4) * 32);
        }
        const int kof = ks * 32 + lg * 8;
#pragma unroll
        for (int mf = 0; mf < 4; ++mf) {
            s8v a = *reinterpret_cast<const s8v*>(&A[mf * 16 + lr][kof]);
            acc[mf][0] = __builtin_amdgcn_mfma_f32_16x16x32_bf16(a, c0, acc[mf][0], 0, 0, 0);
            acc[mf][1] = __builtin_amdgcn_mfma_f32_16x16x32_bf16(a, c1, acc[mf][1], 0, 0, 0);
        }
    }

    // ---- epilogue: per-row sum of tanh(x)*V over this wave's 32 cols ----
    {
        float rs[4][4];
#pragma unroll
        for (int mf = 0; mf < 4; ++mf)
#pragma unroll
            for (int r = 0; r < 4; ++r) rs[mf][r] = 0.f;
#pragma unroll
        for (int mf = 0; mf < 4; ++mf)
#pragma unroll
            for (int nf = 0; nf < 2; ++nf) {
                int col = w * 32 + nf * 16 + lr;
                float hpv = hp[col], vvv = vv[col];
#pragma unroll
                for (int r = 0; r < 4; ++r) {
                    float x = acc[mf][nf][r] + hpv;
                    float e = __expf(2.f * x);
                    rs[mf][r] = fmaf(1.f - 2.f / (e + 1.f), vvv, rs[mf][r]);
                }
            }
#pragma unroll
        for (int off = 1; off < 16; off <<= 1)
#pragma unroll
            for (int mf = 0; mf < 4; ++mf)
#pragma unroll
                for (int r = 0; r < 4; ++r)
                    rs[mf][r] += __shfl_xor(rs[mf][r], off, 64);
        if (lr == 0)
#pragma unroll
            for (int mf = 0; mf < 4; ++mf)
#pragma unroll
                for (int r = 0; r < 4; ++r)
                    spart[w][mf * 16 + lg * 4 + r] = rs[mf][r];
    }
    __syncthreads();

    // ---- scores -> exp -> denominator (wave 0) ----
    if (tid < LT) {
        float s = Vb[0];
#pragma unroll
        for (int ww = 0; ww < 8; ++ww) s += spart[ww][tid];
        float e = __expf(s);
        el[tid] = e;
        el_arr[(size_t)b * Lsz + l0 + tid] = e;
        float es = e;
#pragma unroll
        for (int off = 1; off < 64; off <<= 1) es += __shfl_xor(es, off, 64);
        if (tid == 0) atomicAdd(&den[b], es);
    }
    __syncthreads();

    // ---- context: u32-pair reads, two row-halves, then pc-reduce ----
    {
        const int qr = tid >> 8;            // 0..1 (row half)
        const int d0 = (tid & 255) * 2;
        float a0 = 0.f, a1 = 0.f;
#pragma unroll 8
        for (int li = 0; li < 32; ++li) {
            int l = qr * 32 + li;
            unsigned int pk = *reinterpret_cast<const unsigned int*>(&A[l][d0]);
            float e = el[l];
            a0 = fmaf(e, bf2f(pk & 0xFFFFu), a0);
            a1 = fmaf(e, bf2f(pk >> 16), a1);
        }
        pc[qr][d0]     = a0;
        pc[qr][d0 + 1] = a1;
    }
    __syncthreads();
    atomicAdd(&ctx_acc[b * Dsz + tid], pc[0][tid] + pc[1][tid]);
}

__global__ __launch_bounds__(256) void k_finalize(const float* __restrict__ el_arr,
                                                  const float* __restrict__ den,
                                                  const float* __restrict__ ctx_acc,
                                                  float* __restrict__ ctx,
                                                  float* __restrict__ wout) {
    int b = blockIdx.x, tid = threadIdx.x;
    float inv = 1.f / den[b];
    ctx[(size_t)b * Dsz + tid]       = ctx_acc[b * Dsz + tid] * inv;
    ctx[(size_t)b * Dsz + 256 + tid] = ctx_acc[b * Dsz + 256 + tid] * inv;
#pragma unroll
    for (int i = 0; i < Lsz / 256; ++i) {
        size_t idx = (size_t)b * Lsz + i * 256 + tid;
        wout[idx] = el_arr[idx] * inv;
    }
}

extern "C" void kernel_launch(void* const* d_in, const int* in_sizes, int n_in,
                              void* d_out, int out_size, void* d_ws, size_t ws_size,
                              hipStream_t stream) {
    const float* feat   = (const float*)d_in[0];
    const float* hidden = (const float*)d_in[1];
    const float* W1     = (const float*)d_in[2];
    const float* W1b    = (const float*)d_in[3];
    const float* W2     = (const float*)d_in[4];
    const float* W2b    = (const float*)d_in[5];
    const float* Vk     = (const float*)d_in[6];
    const float* Vb     = (const float*)d_in[7];

    unsigned short* w1t = (unsigned short*)d_ws;
    float* hp_part = (float*)((char*)d_ws + 256 * 1024);
    float* el_arr  = (float*)((char*)d_ws + 512 * 1024);
    float* den     = (float*)((char*)d_ws + 1536 * 1024);
    float* ctx_acc = (float*)((char*)d_ws + 1536 * 1024 + 256);

    float* ctx  = (float*)d_out;              // [64, 512]
    float* wout = ctx + Bsz * Dsz;            // [64, 4096, 1]

    k_prep<<<832, 256, 0, stream>>>(W1, hidden, W2, w1t, hp_part, den, ctx_acc);
    k_score_ctx<<<Bsz * NLB, 512, 0, stream>>>(feat, w1t, hp_part, W1b, W2b,
                                               Vk, Vb, el_arr, den, ctx_acc);
    k_finalize<<<Bsz, 256, 0, stream>>>(el_arr, den, ctx_acc, ctx, wout);
}

// Round 10
// 200.799 us; speedup vs baseline: 1.7975x; 1.0065x over previous
//
#include <hip/hip_runtime.h>

#define Bsz 64
#define Lsz 4096
#define Dsz 512
#define Hsz 512
#define Usz 256
#define LT  64
#define NLB (Lsz / LT)          // 64 L-tiles per batch -> 4096 blocks
#define AW  520                 // LDS row stride (shorts): 1040B, 16B-aligned

typedef __attribute__((ext_vector_type(8))) short s8v;     // bf16x8 MFMA frag
typedef __attribute__((ext_vector_type(4))) float f4v;
typedef __attribute__((ext_vector_type(8))) unsigned short u16x8;

__device__ __forceinline__ unsigned short f2bf(float f) {
    unsigned int u = __float_as_uint(f);
    u += 0x7FFFu + ((u >> 16) & 1u);   // RNE
    return (unsigned short)(u >> 16);
}
__device__ __forceinline__ float bf2f(unsigned int lo16) {
    return __uint_as_float(lo16 << 16);
}

// ws layout
//   [0,     256K)      : W1T bf16 [256][512]
//   [256K,  512K)      : hp_part f32 [4][64][256]
//   [512K, 1536K)      : el_arr f32 [64][4096]
//   [1536K, +256B)     : den f32 [64]
//   [1536K+256, +128K) : ctx_acc f32 [64][512]

// blocks 0..31: W1->W1T transpose via LDS (coalesced both sides).
// blocks 32..287: hproj split-K. 288..351: zero den+ctx_acc.
__global__ __launch_bounds__(256) void k_prep(const float* __restrict__ W1,
                                              const float* __restrict__ hidden,
                                              const float* __restrict__ W2,
                                              unsigned short* __restrict__ W1T,
                                              float* __restrict__ hp_part,
                                              float* __restrict__ den,
                                              float* __restrict__ ctx_acc) {
    int blk = blockIdx.x, tid = threadIdx.x;
    if (blk < 32) {
        __shared__ unsigned short Lt[64][72];   // 64k x 64u bf16 tile, padded
        int kb = blk >> 2, ub = blk & 3;        // k-block 0..7, u-block 0..3
        {
            int rr = tid >> 2, c16 = (tid & 3) * 16;   // row 0..63, 16-float chunk
            const float* src = W1 + (size_t)(kb * 64 + rr) * Usz + ub * 64 + c16;
            f4v v0 = *reinterpret_cast<const f4v*>(src);
            f4v v1 = *reinterpret_cast<const f4v*>(src + 4);
            f4v v2 = *reinterpret_cast<const f4v*>(src + 8);
            f4v v3 = *reinterpret_cast<const f4v*>(src + 12);
            u16x8 o0 = { f2bf(v0.x), f2bf(v0.y), f2bf(v0.z), f2bf(v0.w),
                         f2bf(v1.x), f2bf(v1.y), f2bf(v1.z), f2bf(v1.w) };
            u16x8 o1 = { f2bf(v2.x), f2bf(v2.y), f2bf(v2.z), f2bf(v2.w),
                         f2bf(v3.x), f2bf(v3.y), f2bf(v3.z), f2bf(v3.w) };
            *reinterpret_cast<u16x8*>(&Lt[rr][c16])     = o0;
            *reinterpret_cast<u16x8*>(&Lt[rr][c16 + 8]) = o1;
        }
        __syncthreads();
        {
            int ur = tid >> 2, k16 = (tid & 3) * 16;   // u-row 0..63, 16-k chunk
            u16x8 o0, o1;
#pragma unroll
            for (int i = 0; i < 8; ++i) o0[i] = Lt[k16 + i][ur];
#pragma unroll
            for (int i = 0; i < 8; ++i) o1[i] = Lt[k16 + 8 + i][ur];
            unsigned short* dst = W1T + (size_t)(ub * 64 + ur) * Dsz + kb * 64 + k16;
            *reinterpret_cast<u16x8*>(dst)     = o0;
            *reinterpret_cast<u16x8*>(dst + 8) = o1;
        }
    } else if (blk < 288) {
        int idx = blk - 32;
        int kq = idx >> 6, b = idx & 63;  // K-quarter, batch
        const float* hrow = hidden + (size_t)b * Hsz + kq * 128;
        const float* w2p  = W2 + (size_t)(kq * 128) * Usz + tid;
        float a0 = 0.f, a1 = 0.f, a2 = 0.f, a3 = 0.f;
#pragma unroll 8
        for (int k = 0; k < 128; k += 4) {
            a0 = fmaf(hrow[k + 0], w2p[(size_t)(k + 0) * Usz], a0);
            a1 = fmaf(hrow[k + 1], w2p[(size_t)(k + 1) * Usz], a1);
            a2 = fmaf(hrow[k + 2], w2p[(size_t)(k + 2) * Usz], a2);
            a3 = fmaf(hrow[k + 3], w2p[(size_t)(k + 3) * Usz], a3);
        }
        hp_part[((size_t)kq * Bsz + b) * Usz + tid] = (a0 + a1) + (a2 + a3);
    } else {
        int b = blk - 288;
        if (tid == 0) den[b] = 0.f;
        ctx_acc[b * Dsz + tid] = 0.f;
        ctx_acc[b * Dsz + 256 + tid] = 0.f;
    }
}

// 4096 blocks x 512 thr (8 waves). waves_per_eu(4,4) pins EXACTLY 4 waves/EU
// (2 blocks/CU, matching the 65KiB LDS limit) -> 128-VGPR budget, so the
// depth-4 B prefetch + 32-AGPR accumulator live in registers (R5/R6/R8/R9
// spilled at the compiler's default 64-VGPR choice).
__global__ void __launch_bounds__(512)
__attribute__((amdgpu_waves_per_eu(4, 4))) k_score_ctx(
    const float* __restrict__ feat, const unsigned short* __restrict__ W1T,
    const float* __restrict__ hp_part, const float* __restrict__ W1b,
    const float* __restrict__ W2b, const float* __restrict__ Vk,
    const float* __restrict__ Vb, float* __restrict__ el_arr,
    float* __restrict__ den, float* __restrict__ ctx_acc)
{
    __shared__ __align__(16) unsigned short A[LT][AW];   // 65 KiB
    __shared__ float hp[Usz], vv[Usz];
    __shared__ float spart[8][LT];
    __shared__ float el[LT];
    __shared__ float pc[2][Dsz];

    const int tid  = threadIdx.x;
    const int w    = tid >> 6;
    const int lane = tid & 63;
    const int lr   = lane & 15;
    const int lg   = lane >> 4;
    const int b    = blockIdx.x >> 6;
    const int lb   = blockIdx.x & 63;
    const int l0   = lb * LT;

    if (tid < Usz) {
        const float* hpb = hp_part + (size_t)b * Usz + tid;
        hp[tid] = (hpb[0] + hpb[Bsz * Usz]) + (hpb[2 * Bsz * Usz] + hpb[3 * Bsz * Usz])
                + W1b[tid] + W2b[tid];
        vv[tid] = Vk[tid];
    }

    // ---- stage 64x512 fp32 -> bf16 (b128 LDS writes; transient regs) ----
    {
        const float* fb = feat + ((size_t)b * Lsz + l0) * Dsz;
        const int c8 = (tid & 63) * 8;      // short col (16B store granule)
#pragma unroll 2
        for (int i = 0; i < 8; ++i) {
            int row = i * 8 + w;
            const float* rp = fb + (size_t)row * Dsz + c8;
            f4v v0 = *reinterpret_cast<const f4v*>(rp);
            f4v v1 = *reinterpret_cast<const f4v*>(rp + 4);
            u16x8 o = { f2bf(v0.x), f2bf(v0.y), f2bf(v0.z), f2bf(v0.w),
                        f2bf(v1.x), f2bf(v1.y), f2bf(v1.z), f2bf(v1.w) };
            *reinterpret_cast<u16x8*>(&A[row][c8]) = o;
        }
    }
    __syncthreads();

    // ---- GEMM: 64 rows x this wave's 32 cols x K=512, depth-4 B prefetch ----
    const unsigned short* bp0 = W1T + (size_t)(w * 32 + lr) * Dsz + lg * 8;
    const unsigned short* bp1 = bp0 + 16 * Dsz;
    f4v acc[4][2];
#pragma unroll
    for (int mf = 0; mf < 4; ++mf) {
        acc[mf][0] = (f4v){0.f, 0.f, 0.f, 0.f};
        acc[mf][1] = (f4v){0.f, 0.f, 0.f, 0.f};
    }

    s8v bq[4][2];
#pragma unroll
    for (int i = 0; i < 4; ++i) {
        bq[i][0] = *reinterpret_cast<const s8v*>(bp0 + i * 32);
        bq[i][1] = *reinterpret_cast<const s8v*>(bp1 + i * 32);
    }

#pragma unroll
    for (int ks = 0; ks < 16; ++ks) {
        s8v c0 = bq[ks & 3][0];
        s8v c1 = bq[ks & 3][1];
        if (ks < 12) {
            bq[ks & 3][0] = *reinterpret_cast<const s8v*>(bp0 + (ks + 4) * 32);
            bq[ks & 3][1] = *reinterpret_cast<const s8v*>(bp1 + (ks + 4) * 32);
        }
        const int kof = ks * 32 + lg * 8;
#pragma unroll
        for (int mf = 0; mf < 4; ++mf) {
            s8v a = *reinterpret_cast<const s8v*>(&A[mf * 16 + lr][kof]);
            acc[mf][0] = __builtin_amdgcn_mfma_f32_16x16x32_bf16(a, c0, acc[mf][0], 0, 0, 0);
            acc[mf][1] = __builtin_amdgcn_mfma_f32_16x16x32_bf16(a, c1, acc[mf][1], 0, 0, 0);
        }
    }

    // ---- epilogue: per-row sum of tanh(x)*V over this wave's 32 cols ----
    {
        float rs[4][4];
#pragma unroll
        for (int mf = 0; mf < 4; ++mf)
#pragma unroll
            for (int r = 0; r < 4; ++r) rs[mf][r] = 0.f;
#pragma unroll
        for (int mf = 0; mf < 4; ++mf)
#pragma unroll
            for (int nf = 0; nf < 2; ++nf) {
                int col = w * 32 + nf * 16 + lr;
                float hpv = hp[col], vvv = vv[col];
#pragma unroll
                for (int r = 0; r < 4; ++r) {
                    float x = acc[mf][nf][r] + hpv;
                    float e = __expf(2.f * x);
                    rs[mf][r] = fmaf(1.f - 2.f / (e + 1.f), vvv, rs[mf][r]);
                }
            }
#pragma unroll
        for (int off = 1; off < 16; off <<= 1)
#pragma unroll
            for (int mf = 0; mf < 4; ++mf)
#pragma unroll
                for (int r = 0; r < 4; ++r)
                    rs[mf][r] += __shfl_xor(rs[mf][r], off, 64);
        if (lr == 0)
#pragma unroll
            for (int mf = 0; mf < 4; ++mf)
#pragma unroll
                for (int r = 0; r < 4; ++r)
                    spart[w][mf * 16 + lg * 4 + r] = rs[mf][r];
    }
    __syncthreads();

    // ---- scores -> exp -> denominator (wave 0) ----
    if (tid < LT) {
        float s = Vb[0];
#pragma unroll
        for (int ww = 0; ww < 8; ++ww) s += spart[ww][tid];
        float e = __expf(s);
        el[tid] = e;
        el_arr[(size_t)b * Lsz + l0 + tid] = e;
        float es = e;
#pragma unroll
        for (int off = 1; off < 64; off <<= 1) es += __shfl_xor(es, off, 64);
        if (tid == 0) atomicAdd(&den[b], es);
    }
    __syncthreads();

    // ---- context: u32-pair reads, two row-halves, then pc-reduce ----
    {
        const int qr = tid >> 8;            // 0..1 (row half)
        const int d0 = (tid & 255) * 2;
        float a0 = 0.f, a1 = 0.f;
#pragma unroll 8
        for (int li = 0; li < 32; ++li) {
            int l = qr * 32 + li;
            unsigned int pk = *reinterpret_cast<const unsigned int*>(&A[l][d0]);
            float e = el[l];
            a0 = fmaf(e, bf2f(pk & 0xFFFFu), a0);
            a1 = fmaf(e, bf2f(pk >> 16), a1);
        }
        pc[qr][d0]     = a0;
        pc[qr][d0 + 1] = a1;
    }
    __syncthreads();
    atomicAdd(&ctx_acc[b * Dsz + tid], pc[0][tid] + pc[1][tid]);
}

__global__ __launch_bounds__(256) void k_finalize(const float* __restrict__ el_arr,
                                                  const float* __restrict__ den,
                                                  const float* __restrict__ ctx_acc,
                                                  float* __restrict__ ctx,
                                                  float* __restrict__ wout) {
    int blk = blockIdx.x, tid = threadIdx.x;
    int b = blk >> 2, q = blk & 3;
    float inv = 1.f / den[b];
    size_t base = (size_t)b * Lsz + q * 1024 + tid * 4;
    f4v e4 = *reinterpret_cast<const f4v*>(&el_arr[base]);
    f4v w4 = { e4.x * inv, e4.y * inv, e4.z * inv, e4.w * inv };
    *reinterpret_cast<f4v*>(&wout[base]) = w4;
    if (tid < 128) {
        int d = q * 128 + tid;
        ctx[(size_t)b * Dsz + d] = ctx_acc[b * Dsz + d] * inv;
    }
}

extern "C" void kernel_launch(void* const* d_in, const int* in_sizes, int n_in,
                              void* d_out, int out_size, void* d_ws, size_t ws_size,
                              hipStream_t stream) {
    const float* feat   = (const float*)d_in[0];
    const float* hidden = (const float*)d_in[1];
    const float* W1     = (const float*)d_in[2];
    const float* W1b    = (const float*)d_in[3];
    const float* W2     = (const float*)d_in[4];
    const float* W2b    = (const float*)d_in[5];
    const float* Vk     = (const float*)d_in[6];
    const float* Vb     = (const float*)d_in[7];

    unsigned short* w1t = (unsigned short*)d_ws;
    float* hp_part = (float*)((char*)d_ws + 256 * 1024);
    float* el_arr  = (float*)((char*)d_ws + 512 * 1024);
    float* den     = (float*)((char*)d_ws + 1536 * 1024);
    float* ctx_acc = (float*)((char*)d_ws + 1536 * 1024 + 256);

    float* ctx  = (float*)d_out;              // [64, 512]
    float* wout = ctx + Bsz * Dsz;            // [64, 4096, 1]

    k_prep<<<352, 256, 0, stream>>>(W1, hidden, W2, w1t, hp_part, den, ctx_acc);
    k_score_ctx<<<Bsz * NLB, 512, 0, stream>>>(feat, w1t, hp_part, W1b, W2b,
                                               Vk, Vb, el_arr, den, ctx_acc);
    k_finalize<<<Bsz * 4, 256, 0, stream>>>(el_arr, den, ctx_acc, ctx, wout);
}

// Round 11
// 190.623 us; speedup vs baseline: 1.8934x; 1.0534x over previous
//
#include <hip/hip_runtime.h>

#define Bsz 64
#define Lsz 4096
#define Dsz 512
#define Hsz 512
#define Usz 256
#define LT  64
#define NLB (Lsz / LT)          // 64 L-tiles per batch -> 4096 blocks
#define AW  520                 // LDS row stride (shorts): 1040B, 16B-aligned

typedef __attribute__((ext_vector_type(8))) short s8v;     // bf16x8 MFMA frag
typedef __attribute__((ext_vector_type(4))) float f4v;
typedef __attribute__((ext_vector_type(8))) unsigned short u16x8;

__device__ __forceinline__ unsigned short f2bf(float f) {
    unsigned int u = __float_as_uint(f);
    u += 0x7FFFu + ((u >> 16) & 1u);   // RNE
    return (unsigned short)(u >> 16);
}
__device__ __forceinline__ float bf2f(unsigned int lo16) {
    return __uint_as_float(lo16 << 16);
}
__device__ __forceinline__ void barrier_lds() {
    asm volatile("s_waitcnt lgkmcnt(0)" ::: "memory");
    __builtin_amdgcn_s_barrier();
}

// ws layout
//   [0,     256K)      : W1T bf16 [256][512]
//   [256K,  512K)      : hp_part f32 [4][64][256]
//   [512K, 1536K)      : el_arr f32 [64][4096]
//   [1536K, +256B)     : den f32 [64]
//   [1536K+256, +128K) : ctx_acc f32 [64][512]

// blocks 0..31: W1->W1T transpose via LDS. 32..287: hproj split-K. 288..351: zero acc.
__global__ __launch_bounds__(256) void k_prep(const float* __restrict__ W1,
                                              const float* __restrict__ hidden,
                                              const float* __restrict__ W2,
                                              unsigned short* __restrict__ W1T,
                                              float* __restrict__ hp_part,
                                              float* __restrict__ den,
                                              float* __restrict__ ctx_acc) {
    int blk = blockIdx.x, tid = threadIdx.x;
    if (blk < 32) {
        __shared__ unsigned short Lt[64][72];   // 64k x 64u bf16 tile, padded
        int kb = blk >> 2, ub = blk & 3;        // k-block 0..7, u-block 0..3
        {
            int rr = tid >> 2, c16 = (tid & 3) * 16;
            const float* src = W1 + (size_t)(kb * 64 + rr) * Usz + ub * 64 + c16;
            f4v v0 = *reinterpret_cast<const f4v*>(src);
            f4v v1 = *reinterpret_cast<const f4v*>(src + 4);
            f4v v2 = *reinterpret_cast<const f4v*>(src + 8);
            f4v v3 = *reinterpret_cast<const f4v*>(src + 12);
            u16x8 o0 = { f2bf(v0.x), f2bf(v0.y), f2bf(v0.z), f2bf(v0.w),
                         f2bf(v1.x), f2bf(v1.y), f2bf(v1.z), f2bf(v1.w) };
            u16x8 o1 = { f2bf(v2.x), f2bf(v2.y), f2bf(v2.z), f2bf(v2.w),
                         f2bf(v3.x), f2bf(v3.y), f2bf(v3.z), f2bf(v3.w) };
            *reinterpret_cast<u16x8*>(&Lt[rr][c16])     = o0;
            *reinterpret_cast<u16x8*>(&Lt[rr][c16 + 8]) = o1;
        }
        __syncthreads();
        {
            int ur = tid >> 2, k16 = (tid & 3) * 16;
            u16x8 o0, o1;
#pragma unroll
            for (int i = 0; i < 8; ++i) o0[i] = Lt[k16 + i][ur];
#pragma unroll
            for (int i = 0; i < 8; ++i) o1[i] = Lt[k16 + 8 + i][ur];
            unsigned short* dst = W1T + (size_t)(ub * 64 + ur) * Dsz + kb * 64 + k16;
            *reinterpret_cast<u16x8*>(dst)     = o0;
            *reinterpret_cast<u16x8*>(dst + 8) = o1;
        }
    } else if (blk < 288) {
        int idx = blk - 32;
        int kq = idx >> 6, b = idx & 63;
        const float* hrow = hidden + (size_t)b * Hsz + kq * 128;
        const float* w2p  = W2 + (size_t)(kq * 128) * Usz + tid;
        float a0 = 0.f, a1 = 0.f, a2 = 0.f, a3 = 0.f;
#pragma unroll 8
        for (int k = 0; k < 128; k += 4) {
            a0 = fmaf(hrow[k + 0], w2p[(size_t)(k + 0) * Usz], a0);
            a1 = fmaf(hrow[k + 1], w2p[(size_t)(k + 1) * Usz], a1);
            a2 = fmaf(hrow[k + 2], w2p[(size_t)(k + 2) * Usz], a2);
            a3 = fmaf(hrow[k + 3], w2p[(size_t)(k + 3) * Usz], a3);
        }
        hp_part[((size_t)kq * Bsz + b) * Usz + tid] = (a0 + a1) + (a2 + a3);
    } else {
        int b = blk - 288;
        if (tid == 0) den[b] = 0.f;
        ctx_acc[b * Dsz + tid] = 0.f;
        ctx_acc[b * Dsz + 256 + tid] = 0.f;
    }
}

// 4096 blocks x 512 thr (8 waves), 2 blocks/CU. Block (b,lb): one 64-row tile.
// K split into 4 chunks of 128: stage(c+1) regs overlap GEMM(c); the [64][512]
// tile is filled chunk-by-chunk (columns disjoint) so ctx still sees the full
// tile at the end. vmcnt order per chunk: B(8) then feat(4) -> B-waits never
// drain the HBM loads; st's auto-vmcnt lands after the chunk's 32 MFMAs.
__global__ void __launch_bounds__(512)
__attribute__((amdgpu_waves_per_eu(4, 4))) k_score_ctx(
    const float* __restrict__ feat, const unsigned short* __restrict__ W1T,
    const float* __restrict__ hp_part, const float* __restrict__ W1b,
    const float* __restrict__ W2b, const float* __restrict__ Vk,
    const float* __restrict__ Vb, float* __restrict__ el_arr,
    float* __restrict__ den, float* __restrict__ ctx_acc)
{
    __shared__ __align__(16) unsigned short A[LT][AW];   // 65 KiB
    __shared__ float hp[Usz], vv[Usz];
    __shared__ float spart[8][LT];
    __shared__ float el[LT];
    __shared__ float pc[2][Dsz];

    const int tid  = threadIdx.x;
    const int w    = tid >> 6;
    const int lane = tid & 63;
    const int lr   = lane & 15;
    const int lg   = lane >> 4;
    const int b    = blockIdx.x >> 6;
    const int lb   = blockIdx.x & 63;
    const int l0   = lb * LT;

    const int srow = tid >> 3;            // 0..63
    const int scol = (tid & 7) * 16;      // 0..112 (float col within chunk)
    const float* fb = feat + ((size_t)b * Lsz + l0) * Dsz + (size_t)srow * Dsz + scol;

    // ---- prologue: stage chunk 0 ----
    f4v st[4];
#pragma unroll
    for (int i = 0; i < 4; ++i) st[i] = *reinterpret_cast<const f4v*>(fb + i * 4);

    if (tid < Usz) {
        const float* hpb = hp_part + (size_t)b * Usz + tid;
        hp[tid] = (hpb[0] + hpb[Bsz * Usz]) + (hpb[2 * Bsz * Usz] + hpb[3 * Bsz * Usz])
                + W1b[tid] + W2b[tid];
        vv[tid] = Vk[tid];
    }
    {
        u16x8 o0 = { f2bf(st[0].x), f2bf(st[0].y), f2bf(st[0].z), f2bf(st[0].w),
                     f2bf(st[1].x), f2bf(st[1].y), f2bf(st[1].z), f2bf(st[1].w) };
        u16x8 o1 = { f2bf(st[2].x), f2bf(st[2].y), f2bf(st[2].z), f2bf(st[2].w),
                     f2bf(st[3].x), f2bf(st[3].y), f2bf(st[3].z), f2bf(st[3].w) };
        *reinterpret_cast<u16x8*>(&A[srow][scol])     = o0;
        *reinterpret_cast<u16x8*>(&A[srow][scol + 8]) = o1;
    }
    __syncthreads();

    // ---- pipelined GEMM over 4 K-chunks ----
    const unsigned short* bp0 = W1T + (size_t)(w * 32 + lr) * Dsz + lg * 8;
    const unsigned short* bp1 = bp0 + 16 * Dsz;
    f4v acc[4][2];
#pragma unroll
    for (int mf = 0; mf < 4; ++mf) {
        acc[mf][0] = (f4v){0.f, 0.f, 0.f, 0.f};
        acc[mf][1] = (f4v){0.f, 0.f, 0.f, 0.f};
    }

#pragma unroll
    for (int c = 0; c < 4; ++c) {
        // (1) B-frags for this chunk (L2) — issued FIRST in the vmcnt FIFO
        s8v bq[4][2];
#pragma unroll
        for (int k = 0; k < 4; ++k) {
            bq[k][0] = *reinterpret_cast<const s8v*>(bp0 + (c * 4 + k) * 32);
            bq[k][1] = *reinterpret_cast<const s8v*>(bp1 + (c * 4 + k) * 32);
        }
        __builtin_amdgcn_sched_barrier(0);
        // (2) next-chunk feature loads (HBM) — in flight across the GEMM
        if (c < 3) {
#pragma unroll
            for (int i = 0; i < 4; ++i)
                st[i] = *reinterpret_cast<const f4v*>(fb + (c + 1) * 128 + i * 4);
        }
        __builtin_amdgcn_sched_barrier(0);
        // (3) GEMM chunk c from LDS columns [c*128, c*128+128)
#pragma unroll
        for (int k = 0; k < 4; ++k) {
            const int kof = (c * 4 + k) * 32 + lg * 8;
#pragma unroll
            for (int mf = 0; mf < 4; ++mf) {
                s8v a = *reinterpret_cast<const s8v*>(&A[mf * 16 + lr][kof]);
                acc[mf][0] = __builtin_amdgcn_mfma_f32_16x16x32_bf16(a, bq[k][0], acc[mf][0], 0, 0, 0);
                acc[mf][1] = __builtin_amdgcn_mfma_f32_16x16x32_bf16(a, bq[k][1], acc[mf][1], 0, 0, 0);
            }
        }
        __builtin_amdgcn_sched_barrier(0);
        // (4) write staged chunk c+1 into its (so-far-unused) columns, barrier
        if (c < 3) {
            const int cc = (c + 1) * 128 + scol;
            u16x8 o0 = { f2bf(st[0].x), f2bf(st[0].y), f2bf(st[0].z), f2bf(st[0].w),
                         f2bf(st[1].x), f2bf(st[1].y), f2bf(st[1].z), f2bf(st[1].w) };
            u16x8 o1 = { f2bf(st[2].x), f2bf(st[2].y), f2bf(st[2].z), f2bf(st[2].w),
                         f2bf(st[3].x), f2bf(st[3].y), f2bf(st[3].z), f2bf(st[3].w) };
            *reinterpret_cast<u16x8*>(&A[srow][cc])     = o0;
            *reinterpret_cast<u16x8*>(&A[srow][cc + 8]) = o1;
            barrier_lds();
        }
    }

    // ---- epilogue: per-row sum of tanh(x)*V over this wave's 32 cols ----
    {
        float rs[4][4];
#pragma unroll
        for (int mf = 0; mf < 4; ++mf)
#pragma unroll
            for (int r = 0; r < 4; ++r) rs[mf][r] = 0.f;
#pragma unroll
        for (int mf = 0; mf < 4; ++mf)
#pragma unroll
            for (int nf = 0; nf < 2; ++nf) {
                int col = w * 32 + nf * 16 + lr;
                float hpv = hp[col], vvv = vv[col];
#pragma unroll
                for (int r = 0; r < 4; ++r) {
                    float x = acc[mf][nf][r] + hpv;
                    float e = __expf(2.f * x);
                    rs[mf][r] = fmaf(1.f - 2.f / (e + 1.f), vvv, rs[mf][r]);
                }
            }
#pragma unroll
        for (int off = 1; off < 16; off <<= 1)
#pragma unroll
            for (int mf = 0; mf < 4; ++mf)
#pragma unroll
                for (int r = 0; r < 4; ++r)
                    rs[mf][r] += __shfl_xor(rs[mf][r], off, 64);
        if (lr == 0)
#pragma unroll
            for (int mf = 0; mf < 4; ++mf)
#pragma unroll
                for (int r = 0; r < 4; ++r)
                    spart[w][mf * 16 + lg * 4 + r] = rs[mf][r];
    }
    __syncthreads();

    // ---- scores -> exp -> denominator (wave 0) ----
    if (tid < LT) {
        float s = Vb[0];
#pragma unroll
        for (int ww = 0; ww < 8; ++ww) s += spart[ww][tid];
        float e = __expf(s);
        el[tid] = e;
        el_arr[(size_t)b * Lsz + l0 + tid] = e;
        float es = e;
#pragma unroll
        for (int off = 1; off < 64; off <<= 1) es += __shfl_xor(es, off, 64);
        if (tid == 0) atomicAdd(&den[b], es);
    }
    __syncthreads();

    // ---- context: u32-pair reads, two row-halves, then pc-reduce ----
    {
        const int qr = tid >> 8;            // 0..1 (row half)
        const int d0 = (tid & 255) * 2;
        float a0 = 0.f, a1 = 0.f;
#pragma unroll 8
        for (int li = 0; li < 32; ++li) {
            int l = qr * 32 + li;
            unsigned int pk = *reinterpret_cast<const unsigned int*>(&A[l][d0]);
            float e = el[l];
            a0 = fmaf(e, bf2f(pk & 0xFFFFu), a0);
            a1 = fmaf(e, bf2f(pk >> 16), a1);
        }
        pc[qr][d0]     = a0;
        pc[qr][d0 + 1] = a1;
    }
    __syncthreads();
    atomicAdd(&ctx_acc[b * Dsz + tid], pc[0][tid] + pc[1][tid]);
}

__global__ __launch_bounds__(256) void k_finalize(const float* __restrict__ el_arr,
                                                  const float* __restrict__ den,
                                                  const float* __restrict__ ctx_acc,
                                                  float* __restrict__ ctx,
                                                  float* __restrict__ wout) {
    int blk = blockIdx.x, tid = threadIdx.x;
    int b = blk >> 2, q = blk & 3;
    float inv = 1.f / den[b];
    size_t base = (size_t)b * Lsz + q * 1024 + tid * 4;
    f4v e4 = *reinterpret_cast<const f4v*>(&el_arr[base]);
    f4v w4 = { e4.x * inv, e4.y * inv, e4.z * inv, e4.w * inv };
    *reinterpret_cast<f4v*>(&wout[base]) = w4;
    if (tid < 128) {
        int d = q * 128 + tid;
        ctx[(size_t)b * Dsz + d] = ctx_acc[b * Dsz + d] * inv;
    }
}

extern "C" void kernel_launch(void* const* d_in, const int* in_sizes, int n_in,
                              void* d_out, int out_size, void* d_ws, size_t ws_size,
                              hipStream_t stream) {
    const float* feat   = (const float*)d_in[0];
    const float* hidden = (const float*)d_in[1];
    const float* W1     = (const float*)d_in[2];
    const float* W1b    = (const float*)d_in[3];
    const float* W2     = (const float*)d_in[4];
    const float* W2b    = (const float*)d_in[5];
    const float* Vk     = (const float*)d_in[6];
    const float* Vb     = (const float*)d_in[7];

    unsigned short* w1t = (unsigned short*)d_ws;
    float* hp_part = (float*)((char*)d_ws + 256 * 1024);
    float* el_arr  = (float*)((char*)d_ws + 512 * 1024);
    float* den     = (float*)((char*)d_ws + 1536 * 1024);
    float* ctx_acc = (float*)((char*)d_ws + 1536 * 1024 + 256);

    float* ctx  = (float*)d_out;              // [64, 512]
    float* wout = ctx + Bsz * Dsz;            // [64, 4096, 1]

    k_prep<<<352, 256, 0, stream>>>(W1, hidden, W2, w1t, hp_part, den, ctx_acc);
    k_score_ctx<<<Bsz * NLB, 512, 0, stream>>>(feat, w1t, hp_part, W1b, W2b,
                                               Vk, Vb, el_arr, den, ctx_acc);
    k_finalize<<<Bsz * 4, 256, 0, stream>>>(el_arr, den, ctx_acc, ctx, wout);
}